// Round 7
// baseline (249.471 us; speedup 1.0000x reference)
//
#include <hip/hip_runtime.h>

typedef unsigned short u16;
typedef __attribute__((ext_vector_type(8))) unsigned short u16x8;
typedef __attribute__((ext_vector_type(2))) unsigned int u32x2;
typedef __attribute__((ext_vector_type(8))) __bf16 bf16x8;
typedef __attribute__((ext_vector_type(4))) float f32x4;

#define T_SEQ 2048
#define WINDOW 1024
// 0.125 * log2(e)
#define QSCALE 0.18033688011112042f

static __device__ __forceinline__ u16 f2bf(float f) {
    unsigned int u = __float_as_uint(f);
    u += 0x7fffu + ((u >> 16) & 1u);
    return (u16)(u >> 16);
}
static __device__ __forceinline__ float bf2f(u16 h) {
    return __uint_as_float(((unsigned int)h) << 16);
}
static __device__ __forceinline__ bf16x8 ld_bf8(const u16* p) {
    return __builtin_bit_cast(bf16x8, *(const u16x8*)p);
}
static __device__ __forceinline__ unsigned int cvt_pk_bf16(float lo, float hi) {
    unsigned int r;
    asm("v_cvt_pk_bf16_f32 %0, %1, %2" : "=v"(r) : "v"(lo), "v"(hi));
    return r;
}
static __device__ __forceinline__ float exp2f_raw(float x) {
#if __has_builtin(__builtin_amdgcn_exp2f)
    return __builtin_amdgcn_exp2f(x);
#else
    return exp2f(x);
#endif
}
// async global -> LDS, 16B per lane (wave-uniform LDS base + lane*16)
static __device__ __forceinline__ void g2l16(const void* g, void* l) {
    __builtin_amdgcn_global_load_lds(
        (const __attribute__((address_space(1))) void*)g,
        (__attribute__((address_space(3))) void*)l, 16, 0, 0);
}

// ---------------- RoPE cos/sin table: float2[2048][32] ----------------
__global__ __launch_bounds__(256)
void rope_tab_kernel(float2* __restrict__ tab)
{
    int idx = blockIdx.x * 256 + threadIdx.x;   // 65536
    int t = idx >> 5, dp = idx & 31;
    float inv_freq = __expf(-dp * 0.28782313662425574f); // ln(10000)/32
    float ang = (float)t * inv_freq;
    float s, c;
    sincosf(ang, &s, &c);
    tab[idx] = make_float2(c, s);
}

// ---------------- x fp32 -> bf16 (same layout) ----------------
__global__ __launch_bounds__(256)
void convert_x(const float* __restrict__ src, u16* __restrict__ dst)
{
    int i8 = blockIdx.x * 256 + threadIdx.x;
    size_t base = (size_t)i8 * 8;
    float4 a = *(const float4*)(src + base);
    float4 b = *(const float4*)(src + base + 4);
    u16x8 o = { f2bf(a.x), f2bf(a.y), f2bf(a.z), f2bf(a.w),
                f2bf(b.x), f2bf(b.y), f2bf(b.z), f2bf(b.w) };
    *(u16x8*)(dst + base) = o;
}

// ---------------- all W fp32 [2048][N] -> bf16 transposed [N][2048], scaled ----------------
__global__ __launch_bounds__(256)
void trans_conv_all(const float* __restrict__ Wq, const float* __restrict__ Wk,
                    const float* __restrict__ Wv, const float* __restrict__ Wo,
                    u16* __restrict__ WqkvT, u16* __restrict__ WoT)
{
    __shared__ __align__(16) u16 tile[64][72];
    const int z = blockIdx.z;
    const float* src; int N; float scale; u16* dst;
    if (z == 0)      { src = Wq; N = 2048; scale = QSCALE; dst = WqkvT; }
    else if (z == 1) { src = Wk; N = 512;  scale = 1.f;    dst = WqkvT + (size_t)2048 * 2048; }
    else if (z == 2) { src = Wv; N = 512;  scale = 1.f;    dst = WqkvT + (size_t)2560 * 2048; }
    else             { src = Wo; N = 2048; scale = 1.f;    dst = WoT; }
    if ((int)blockIdx.y * 64 >= N) return;

    const int tid = threadIdx.x;
    const int k0 = blockIdx.x * 64;
    const int n0 = blockIdx.y * 64;
    {
        int r = tid >> 2, c0 = (tid & 3) * 16;
        const float* sp = src + (size_t)(k0 + r) * N + n0 + c0;
        float4 v0 = *(const float4*)(sp + 0);
        float4 v1 = *(const float4*)(sp + 4);
        float4 v2 = *(const float4*)(sp + 8);
        float4 v3 = *(const float4*)(sp + 12);
        u16x8 s0 = { f2bf(v0.x * scale), f2bf(v0.y * scale), f2bf(v0.z * scale), f2bf(v0.w * scale),
                     f2bf(v1.x * scale), f2bf(v1.y * scale), f2bf(v1.z * scale), f2bf(v1.w * scale) };
        u16x8 s1 = { f2bf(v2.x * scale), f2bf(v2.y * scale), f2bf(v2.z * scale), f2bf(v2.w * scale),
                     f2bf(v3.x * scale), f2bf(v3.y * scale), f2bf(v3.z * scale), f2bf(v3.w * scale) };
        *(u16x8*)&tile[r][c0]     = s0;
        *(u16x8*)&tile[r][c0 + 8] = s1;
    }
    __syncthreads();
    {
        int n = tid >> 2, j0 = (tid & 3) * 16;
        u16x8 o0, o1;
        #pragma unroll
        for (int i = 0; i < 8; ++i) o0[i] = tile[j0 + i][n];
        #pragma unroll
        for (int i = 0; i < 8; ++i) o1[i] = tile[j0 + 8 + i][n];
        u16* dp = dst + (size_t)(n0 + n) * 2048 + k0 + j0;
        *(u16x8*)dp       = o0;
        *(u16x8*)(dp + 8) = o1;
    }
}

// ---------------- shared GEMM compute step ----------------
__device__ __forceinline__ void gemm_step(const u16 (*Al)[32], const u16 (*Bl)[32],
                                          int lane, int wm, int wn, f32x4 acc[4][4])
{
    bf16x8 af[4], bfr[4];
    #pragma unroll
    for (int m = 0; m < 4; ++m)
        af[m] = ld_bf8(&Al[wm * 64 + m * 16 + (lane & 15)][(lane >> 4) * 8]);
    #pragma unroll
    for (int n = 0; n < 4; ++n)
        bfr[n] = ld_bf8(&Bl[wn * 64 + n * 16 + (lane & 15)][(lane >> 4) * 8]);
    #pragma unroll
    for (int m = 0; m < 4; ++m)
        #pragma unroll
        for (int n = 0; n < 4; ++n)
            acc[m][n] = __builtin_amdgcn_mfma_f32_16x16x32_bf16(af[m], bfr[n], acc[m][n], 0, 0, 0);
}

// ---------------- QKV GEMM: 2-phase dbuf + XCD swizzle + fused RoPE ----------------
__global__ __launch_bounds__(256)
void qkv_gemm(const u16* __restrict__ xb, const u16* __restrict__ Wt,
              const float2* __restrict__ tab,
              u16* __restrict__ Qb, u16* __restrict__ Kb, u16* __restrict__ Vb)
{
    __shared__ __align__(16) u16 Al[2][128][32];
    __shared__ __align__(16) u16 Bl[2][128][32];
    const int tid = threadIdx.x;
    const int lane = tid & 63;
    const int w = tid >> 6;
    const int wm = w >> 1, wn = w & 1;
    // bijective XCD swizzle: 768 wgs -> 96 contiguous per XCD (3 B-panels each)
    const int g = blockIdx.x;
    const int swz = (g & 7) * 96 + (g >> 3);
    const int m0  = (swz & 31) * 128;
    const int n0g = (swz >> 5) * 128;

    f32x4 acc[4][4] = {};

    const int srow = w * 32 + (lane >> 2);
    const int scol = (lane & 3) * 8;
    const u16* ag0 = xb + (size_t)(m0 + srow) * 2048 + scol;
    const u16* bg0 = Wt + (size_t)(n0g + srow) * 2048 + scol;

    #define STAGE_QKV(sel, kb) do { \
        g2l16(ag0 + (kb),             &Al[sel][w * 32][0]); \
        g2l16(ag0 + (kb) + 16 * 2048, &Al[sel][w * 32 + 16][0]); \
        g2l16(bg0 + (kb),             &Bl[sel][w * 32][0]); \
        g2l16(bg0 + (kb) + 16 * 2048, &Bl[sel][w * 32 + 16][0]); } while (0)

    STAGE_QKV(0, 0);
    __syncthreads();
    for (int kb = 0; kb < 2048; kb += 64) {
        STAGE_QKV(1, kb + 32);                       // issue next while computing cur
        gemm_step(Al[0], Bl[0], lane, wm, wn, acc);
        __syncthreads();                             // drains vmcnt: buf1 ready
        if (kb + 64 < 2048) STAGE_QKV(0, kb + 64);
        gemm_step(Al[1], Bl[1], lane, wm, wn, acc);
        __syncthreads();
    }
    #undef STAGE_QKV

    const int r0 = (lane >> 4) * 4;
    const int c0 = lane & 15;
    const int colbase = n0g + wn * 64;
    const bool isV = (n0g >= 2560);
    const bool isQ = (n0g < 2048);

    #pragma unroll
    for (int m = 0; m < 4; ++m) {
        #pragma unroll
        for (int r = 0; r < 4; ++r) {
            int rw = m0 + wm * 64 + m * 16 + r0 + r;
            int b = rw >> 11, t = rw & 2047;
            if (!isV) {
                #pragma unroll
                for (int np = 0; np < 2; ++np) {
                    int dp = np * 16 + c0;
                    float2 cs = tab[t * 32 + dp];
                    float x1 = acc[m][np][r];
                    float x2 = acc[m][np + 2][r];
                    float lo = x1 * cs.x - x2 * cs.y;
                    float hi = x2 * cs.x + x1 * cs.y;
                    if (isQ) {
                        int h = colbase >> 6;
                        size_t base = (((size_t)b * 32 + h) * 2048 + t) * 64 + dp;
                        Qb[base]      = f2bf(lo);
                        Qb[base + 32] = f2bf(hi);
                    } else {
                        int hk = (colbase - 2048) >> 6;
                        size_t base = (((size_t)b * 8 + hk) * 2048 + t) * 64 + dp;
                        Kb[base]      = f2bf(lo);
                        Kb[base + 32] = f2bf(hi);
                    }
                }
            } else {
                #pragma unroll
                for (int n = 0; n < 4; ++n) {
                    int c2 = colbase + n * 16 + c0 - 2560;
                    int hk = c2 >> 6, d = c2 & 63;
                    Vb[(((size_t)b * 8 + hk) * 2048 + t) * 64 + d] = f2bf(acc[m][n][r]);
                }
            }
        }
    }
}

// ---------------- V transpose: (b,hk,t,d) -> (b,hk,d,t) ----------------
__global__ __launch_bounds__(256)
void vtrans(const u16* __restrict__ Vb, u16* __restrict__ Vt)
{
    __shared__ __align__(16) u16 tile[64][68];
    const int tid = threadIdx.x;
    const int t0 = blockIdx.x * 64;
    const size_t base = (size_t)blockIdx.y * 2048 * 64;
    {
        int r = tid >> 2, c0 = (tid & 3) * 16;
        const u16* src = Vb + base + (size_t)(t0 + r) * 64 + c0;
        *(u16x8*)&tile[r][c0]     = *(const u16x8*)src;
        *(u16x8*)&tile[r][c0 + 8] = *(const u16x8*)(src + 8);
    }
    __syncthreads();
    {
        int d = tid >> 2, j0 = (tid & 3) * 16;
        u16x8 o0, o1;
        #pragma unroll
        for (int i = 0; i < 8; ++i) o0[i] = tile[j0 + i][d];
        #pragma unroll
        for (int i = 0; i < 8; ++i) o1[i] = tile[j0 + 8 + i][d];
        u16* dst = Vt + base + (size_t)d * 2048 + t0 + j0;
        *(u16x8*)dst       = o0;
        *(u16x8*)(dst + 8) = o1;
    }
}

// ---------------- Flash attention: swapped QK^T, log2-domain, XOR-swizzled LDS ----------------
__global__ __launch_bounds__(256)
void attn_kernel(const u16* __restrict__ Qb, const u16* __restrict__ Kb,
                 const u16* __restrict__ Vt, u16* __restrict__ AO)
{
    __shared__ __align__(16) u16 Kl[64][64];    // XOR-swizzled 16B chunks
    __shared__ __align__(16) u16 Vl[64][64];    // Vl[d][j], swizzled
    __shared__ __align__(16) u16 Pl[4][16][64]; // per-wave [q][k], swizzled

    const int tid = threadIdx.x;
    const int lane = tid & 63;
    const int w = tid >> 6;
    const int q = lane & 15;
    const int hq = lane >> 4;
    const int q0 = blockIdx.x * 64;
    const int bh = blockIdx.y;
    const int b = bh >> 5, h = bh & 31;
    const int hk = h >> 2;
    const size_t qbase  = (size_t)bh * 2048 * 64;
    const size_t kvbase = ((size_t)b * 8 + hk) * 2048 * 64;

    const int sj = tid >> 2;
    const int sd = (tid & 3) * 16;
    const int sc0 = (tid & 3) * 2;
    const int sw0 = ((sc0    ) ^ (sj & 7)) << 3;
    const int sw1 = ((sc0 + 1) ^ (sj & 7)) << 3;
    const int ca0 = ((hq    ) ^ (q & 7)) << 3;
    const int ca1 = ((hq + 4) ^ (q & 7)) << 3;

    bf16x8 qf0, qf1;
    {
        const u16* qp = Qb + qbase + (size_t)(q0 + w * 16 + q) * 64 + hq * 8;
        qf0 = ld_bf8(qp);
        qf1 = ld_bf8(qp + 32);
    }

    float mrun = -1e20f, lrun = 0.f;
    f32x4 o[4] = {};

    int kbeg = q0 - (WINDOW - 1);
    if (kbeg < 0) kbeg = 0;
    kbeg &= ~63;
    const int kend = q0 + 64;

    const int wrow_min = q0 + w * 16;
    const int wrow_max = wrow_min + 15;
    const int iq = wrow_min + q;

    u16x8 kr0, kr1, vr0, vr1;
    {
        const u16* kg = Kb + kvbase + (size_t)(kbeg + sj) * 64 + sd;
        kr0 = *(const u16x8*)kg;
        kr1 = *(const u16x8*)(kg + 8);
        const u16* vg = Vt + kvbase + (size_t)sj * 2048 + kbeg + sd;
        vr0 = *(const u16x8*)vg;
        vr1 = *(const u16x8*)(vg + 8);
    }
    *(u16x8*)&Kl[sj][sw0] = kr0;
    *(u16x8*)&Kl[sj][sw1] = kr1;
    *(u16x8*)&Vl[sj][sw0] = vr0;
    *(u16x8*)&Vl[sj][sw1] = vr1;
    __syncthreads();

    for (int k0 = kbeg; k0 < kend; k0 += 64) {
        const bool has_next = (k0 + 64 < kend);
        if (has_next) {
            const u16* kg = Kb + kvbase + (size_t)(k0 + 64 + sj) * 64 + sd;
            kr0 = *(const u16x8*)kg;
            kr1 = *(const u16x8*)(kg + 8);
            const u16* vg = Vt + kvbase + (size_t)sj * 2048 + k0 + 64 + sd;
            vr0 = *(const u16x8*)vg;
            vr1 = *(const u16x8*)(vg + 8);
        }

        bool active = (k0 <= wrow_max) && (k0 + 63 >= wrow_min - (WINDOW - 1));
        if (active) {
            f32x4 s[4];
            #pragma unroll
            for (int nf = 0; nf < 4; ++nf) {
                bf16x8 kb0 = ld_bf8(&Kl[nf * 16 + q][ca0]);
                bf16x8 kb1 = ld_bf8(&Kl[nf * 16 + q][ca1]);
                f32x4 a = {};
                a = __builtin_amdgcn_mfma_f32_16x16x32_bf16(kb0, qf0, a, 0, 0, 0);
                a = __builtin_amdgcn_mfma_f32_16x16x32_bf16(kb1, qf1, a, 0, 0, 0);
                s[nf] = a;
            }
            bool need_causal = (k0 + 63 > wrow_min);
            bool need_window = (wrow_max - k0) >= WINDOW;
            if (need_causal || need_window) {
                #pragma unroll
                for (int nf = 0; nf < 4; ++nf) {
                    #pragma unroll
                    for (int r = 0; r < 4; ++r) {
                        int j = k0 + nf * 16 + hq * 4 + r;
                        bool ok = (j <= iq) && (iq - j < WINDOW);
                        if (!ok) s[nf][r] = -1e30f;
                    }
                }
            }
            float tmax = s[0][0];
            #pragma unroll
            for (int nf = 0; nf < 4; ++nf)
                #pragma unroll
                for (int r = 0; r < 4; ++r) tmax = fmaxf(tmax, s[nf][r]);
            tmax = fmaxf(tmax, __shfl_xor(tmax, 16));
            tmax = fmaxf(tmax, __shfl_xor(tmax, 32));

            bool skip = __all(tmax <= mrun + 11.5f);
            float mnew = skip ? mrun : fmaxf(mrun, tmax);

            float tsum = 0.f;
            #pragma unroll
            for (int nf = 0; nf < 4; ++nf) {
                float p0 = exp2f_raw(s[nf][0] - mnew);
                float p1 = exp2f_raw(s[nf][1] - mnew);
                float p2 = exp2f_raw(s[nf][2] - mnew);
                float p3 = exp2f_raw(s[nf][3] - mnew);
                tsum += (p0 + p1) + (p2 + p3);
                u32x2 pw = { cvt_pk_bf16(p0, p1), cvt_pk_bf16(p2, p3) };
                int cpw = (((2 * nf + (hq >> 1)) ^ (q & 7)) << 3) + ((hq & 1) << 2);
                *(u32x2*)&Pl[w][q][cpw] = pw;
            }
            tsum += __shfl_xor(tsum, 16);
            tsum += __shfl_xor(tsum, 32);

            if (skip) {
                lrun += tsum;
            } else {
                float sc = exp2f_raw(mrun - mnew);
                mrun = mnew;
                lrun = lrun * sc + tsum;
                float osc[4];
                #pragma unroll
                for (int r = 0; r < 4; ++r)
                    osc[r] = __shfl(sc, (lane & 48) + hq * 4 + r);
                #pragma unroll
                for (int nf = 0; nf < 4; ++nf)
                    #pragma unroll
                    for (int r = 0; r < 4; ++r)
                        o[nf][r] *= osc[r];
            }

            bf16x8 pa0 = ld_bf8(&Pl[w][q][ca0]);
            bf16x8 pa1 = ld_bf8(&Pl[w][q][ca1]);
            #pragma unroll
            for (int nf = 0; nf < 4; ++nf) {
                bf16x8 vb0 = ld_bf8(&Vl[nf * 16 + q][ca0]);
                bf16x8 vb1 = ld_bf8(&Vl[nf * 16 + q][ca1]);
                o[nf] = __builtin_amdgcn_mfma_f32_16x16x32_bf16(pa0, vb0, o[nf], 0, 0, 0);
                o[nf] = __builtin_amdgcn_mfma_f32_16x16x32_bf16(pa1, vb1, o[nf], 0, 0, 0);
            }
        }
        __syncthreads();
        if (has_next) {
            *(u16x8*)&Kl[sj][sw0] = kr0;
            *(u16x8*)&Kl[sj][sw1] = kr1;
            *(u16x8*)&Vl[sj][sw0] = vr0;
            *(u16x8*)&Vl[sj][sw1] = vr1;
        }
        __syncthreads();
    }

    float linv_own = 1.f / lrun;
    float linv[4];
    #pragma unroll
    for (int r = 0; r < 4; ++r)
        linv[r] = __shfl(linv_own, (lane & 48) + hq * 4 + r);
    #pragma unroll
    for (int nf = 0; nf < 4; ++nf) {
        #pragma unroll
        for (int r = 0; r < 4; ++r) {
            int i = q0 + w * 16 + hq * 4 + r;
            int d = nf * 16 + q;
            AO[((size_t)b * 2048 + i) * 2048 + h * 64 + d] = f2bf(o[nf][r] * linv[r]);
        }
    }
}

// ---------------- Output projection: 2-phase dbuf + XCD swizzle ----------------
__global__ __launch_bounds__(256)
void out_gemm(const u16* __restrict__ A, const u16* __restrict__ Wt, float* __restrict__ C)
{
    __shared__ __align__(16) u16 Al[2][128][32];
    __shared__ __align__(16) u16 Bl[2][128][32];
    const int tid = threadIdx.x;
    const int lane = tid & 63;
    const int w = tid >> 6;
    const int wm = w >> 1, wn = w & 1;
    // 512 wgs -> 64 contiguous per XCD (2 B-panels each)
    const int g = blockIdx.x;
    const int swz = (g & 7) * 64 + (g >> 3);
    const int m0 = (swz & 31) * 128;
    const int n0 = (swz >> 5) * 128;

    f32x4 acc[4][4] = {};

    const int srow = w * 32 + (lane >> 2);
    const int scol = (lane & 3) * 8;
    const u16* ag0 = A  + (size_t)(m0 + srow) * 2048 + scol;
    const u16* bg0 = Wt + (size_t)(n0 + srow) * 2048 + scol;

    #define STAGE_O(sel, kb) do { \
        g2l16(ag0 + (kb),             &Al[sel][w * 32][0]); \
        g2l16(ag0 + (kb) + 16 * 2048, &Al[sel][w * 32 + 16][0]); \
        g2l16(bg0 + (kb),             &Bl[sel][w * 32][0]); \
        g2l16(bg0 + (kb) + 16 * 2048, &Bl[sel][w * 32 + 16][0]); } while (0)

    STAGE_O(0, 0);
    __syncthreads();
    for (int kb = 0; kb < 2048; kb += 64) {
        STAGE_O(1, kb + 32);
        gemm_step(Al[0], Bl[0], lane, wm, wn, acc);
        __syncthreads();
        if (kb + 64 < 2048) STAGE_O(0, kb + 64);
        gemm_step(Al[1], Bl[1], lane, wm, wn, acc);
        __syncthreads();
    }
    #undef STAGE_O

    const int r0 = (lane >> 4) * 4;
    const int c0 = lane & 15;
    #pragma unroll
    for (int m = 0; m < 4; ++m) {
        #pragma unroll
        for (int n = 0; n < 4; ++n) {
            #pragma unroll
            for (int r = 0; r < 4; ++r) {
                int rw = m0 + wm * 64 + m * 16 + r0 + r;
                int col = n0 + wn * 64 + n * 16 + c0;
                C[(size_t)rw * 2048 + col] = acc[m][n][r];
            }
        }
    }
}

extern "C" void kernel_launch(void* const* d_in, const int* in_sizes, int n_in,
                              void* d_out, int out_size, void* d_ws, size_t ws_size,
                              hipStream_t stream)
{
    const float* x  = (const float*)d_in[0];
    const float* Wq = (const float*)d_in[1];
    const float* Wk = (const float*)d_in[2];
    const float* Wv = (const float*)d_in[3];
    const float* Wo = (const float*)d_in[4];
    float* out = (float*)d_out;

    u16* Qb    = (u16*)d_ws;                              //  8,388,608
    u16* Kb    = Qb    + (size_t)8388608;                 //  2,097,152
    u16* Vb    = Kb    + (size_t)2097152;                 //  2,097,152
    u16* Vt    = Vb    + (size_t)2097152;                 //  2,097,152
    u16* AO    = Vt    + (size_t)2097152;                 //  8,388,608
    u16* xb    = AO    + (size_t)8388608;                 //  8,388,608
    u16* WqkvT = xb    + (size_t)8388608;                 //  6,291,456  [3072][2048]
    u16* WoT   = WqkvT + (size_t)6291456;                 //  4,194,304  [2048][2048]
    float2* tab = (float2*)(WoT + (size_t)4194304);       //  512KB

    rope_tab_kernel<<<256, 256, 0, stream>>>(tab);
    convert_x<<<4096, 256, 0, stream>>>(x, xb);
    trans_conv_all<<<dim3(32, 32, 4), 256, 0, stream>>>(Wq, Wk, Wv, Wo, WqkvT, WoT);

    qkv_gemm<<<768, 256, 0, stream>>>(xb, WqkvT, tab, Qb, Kb, Vb);
    vtrans<<<dim3(32, 16), 256, 0, stream>>>(Vb, Vt);
    attn_kernel<<<dim3(32, 64), 256, 0, stream>>>(Qb, Kb, Vt, AO);
    out_gemm<<<512, 256, 0, stream>>>(AO, WoT, out);
}

// Round 8
// 235.973 us; speedup vs baseline: 1.0572x; 1.0572x over previous
//
#include <hip/hip_runtime.h>

typedef unsigned short u16;
typedef __attribute__((ext_vector_type(8))) unsigned short u16x8;
typedef __attribute__((ext_vector_type(2))) unsigned int u32x2;
typedef __attribute__((ext_vector_type(8))) __bf16 bf16x8;
typedef __attribute__((ext_vector_type(4))) float f32x4;

#define T_SEQ 2048
#define WINDOW 1024
// 0.125 * log2(e)
#define QSCALE 0.18033688011112042f

static __device__ __forceinline__ u16 f2bf(float f) {
    unsigned int u = __float_as_uint(f);
    u += 0x7fffu + ((u >> 16) & 1u);
    return (u16)(u >> 16);
}
static __device__ __forceinline__ float bf2f(u16 h) {
    return __uint_as_float(((unsigned int)h) << 16);
}
static __device__ __forceinline__ bf16x8 ld_bf8(const u16* p) {
    return __builtin_bit_cast(bf16x8, *(const u16x8*)p);
}
static __device__ __forceinline__ unsigned int cvt_pk_bf16(float lo, float hi) {
    unsigned int r;
    asm("v_cvt_pk_bf16_f32 %0, %1, %2" : "=v"(r) : "v"(lo), "v"(hi));
    return r;
}
static __device__ __forceinline__ float exp2f_raw(float x) {
#if __has_builtin(__builtin_amdgcn_exp2f)
    return __builtin_amdgcn_exp2f(x);
#else
    return exp2f(x);
#endif
}
// async global -> LDS, 16B per lane (wave-uniform LDS base + lane*16)
static __device__ __forceinline__ void g2l16(const void* g, void* l) {
    __builtin_amdgcn_global_load_lds(
        (const __attribute__((address_space(1))) void*)g,
        (__attribute__((address_space(3))) void*)l, 16, 0, 0);
}

// ---------------- RoPE cos/sin table: float2[2048][32] ----------------
__global__ __launch_bounds__(256)
void rope_tab_kernel(float2* __restrict__ tab)
{
    int idx = blockIdx.x * 256 + threadIdx.x;   // 65536
    int t = idx >> 5, dp = idx & 31;
    float inv_freq = __expf(-dp * 0.28782313662425574f); // ln(10000)/32
    float ang = (float)t * inv_freq;
    float s, c;
    sincosf(ang, &s, &c);
    tab[idx] = make_float2(c, s);
}

// ---------------- x fp32 -> bf16 (same layout) ----------------
__global__ __launch_bounds__(256)
void convert_x(const float* __restrict__ src, u16* __restrict__ dst)
{
    int i8 = blockIdx.x * 256 + threadIdx.x;
    size_t base = (size_t)i8 * 8;
    float4 a = *(const float4*)(src + base);
    float4 b = *(const float4*)(src + base + 4);
    u16x8 o = { f2bf(a.x), f2bf(a.y), f2bf(a.z), f2bf(a.w),
                f2bf(b.x), f2bf(b.y), f2bf(b.z), f2bf(b.w) };
    *(u16x8*)(dst + base) = o;
}

// ---------------- all W fp32 [2048][N] -> bf16 transposed [N][2048], scaled ----------------
__global__ __launch_bounds__(256)
void trans_conv_all(const float* __restrict__ Wq, const float* __restrict__ Wk,
                    const float* __restrict__ Wv, const float* __restrict__ Wo,
                    u16* __restrict__ WqkvT, u16* __restrict__ WoT)
{
    __shared__ __align__(16) u16 tile[64][72];
    const int z = blockIdx.z;
    const float* src; int N; float scale; u16* dst;
    if (z == 0)      { src = Wq; N = 2048; scale = QSCALE; dst = WqkvT; }
    else if (z == 1) { src = Wk; N = 512;  scale = 1.f;    dst = WqkvT + (size_t)2048 * 2048; }
    else if (z == 2) { src = Wv; N = 512;  scale = 1.f;    dst = WqkvT + (size_t)2560 * 2048; }
    else             { src = Wo; N = 2048; scale = 1.f;    dst = WoT; }
    if ((int)blockIdx.y * 64 >= N) return;

    const int tid = threadIdx.x;
    const int k0 = blockIdx.x * 64;
    const int n0 = blockIdx.y * 64;
    {
        int r = tid >> 2, c0 = (tid & 3) * 16;
        const float* sp = src + (size_t)(k0 + r) * N + n0 + c0;
        float4 v0 = *(const float4*)(sp + 0);
        float4 v1 = *(const float4*)(sp + 4);
        float4 v2 = *(const float4*)(sp + 8);
        float4 v3 = *(const float4*)(sp + 12);
        u16x8 s0 = { f2bf(v0.x * scale), f2bf(v0.y * scale), f2bf(v0.z * scale), f2bf(v0.w * scale),
                     f2bf(v1.x * scale), f2bf(v1.y * scale), f2bf(v1.z * scale), f2bf(v1.w * scale) };
        u16x8 s1 = { f2bf(v2.x * scale), f2bf(v2.y * scale), f2bf(v2.z * scale), f2bf(v2.w * scale),
                     f2bf(v3.x * scale), f2bf(v3.y * scale), f2bf(v3.z * scale), f2bf(v3.w * scale) };
        *(u16x8*)&tile[r][c0]     = s0;
        *(u16x8*)&tile[r][c0 + 8] = s1;
    }
    __syncthreads();
    {
        int n = tid >> 2, j0 = (tid & 3) * 16;
        u16x8 o0, o1;
        #pragma unroll
        for (int i = 0; i < 8; ++i) o0[i] = tile[j0 + i][n];
        #pragma unroll
        for (int i = 0; i < 8; ++i) o1[i] = tile[j0 + 8 + i][n];
        u16* dp = dst + (size_t)(n0 + n) * 2048 + k0 + j0;
        *(u16x8*)dp       = o0;
        *(u16x8*)(dp + 8) = o1;
    }
}

// ---------------- shared GEMM compute step ----------------
__device__ __forceinline__ void gemm_step(const u16 (*Al)[32], const u16 (*Bl)[32],
                                          int lane, int wm, int wn, f32x4 acc[4][4])
{
    bf16x8 af[4], bfr[4];
    #pragma unroll
    for (int m = 0; m < 4; ++m)
        af[m] = ld_bf8(&Al[wm * 64 + m * 16 + (lane & 15)][(lane >> 4) * 8]);
    #pragma unroll
    for (int n = 0; n < 4; ++n)
        bfr[n] = ld_bf8(&Bl[wn * 64 + n * 16 + (lane & 15)][(lane >> 4) * 8]);
    #pragma unroll
    for (int m = 0; m < 4; ++m)
        #pragma unroll
        for (int n = 0; n < 4; ++n)
            acc[m][n] = __builtin_amdgcn_mfma_f32_16x16x32_bf16(af[m], bfr[n], acc[m][n], 0, 0, 0);
}

// ---------------- QKV GEMM: 2-phase dbuf, natural grid, fused RoPE ----------------
__global__ __launch_bounds__(256)
void qkv_gemm(const u16* __restrict__ xb, const u16* __restrict__ Wt,
              const float2* __restrict__ tab,
              u16* __restrict__ Qb, u16* __restrict__ Kb, u16* __restrict__ Vb)
{
    __shared__ __align__(16) u16 Al[2][128][32];
    __shared__ __align__(16) u16 Bl[2][128][32];
    const int tid = threadIdx.x;
    const int lane = tid & 63;
    const int w = tid >> 6;
    const int wm = w >> 1, wn = w & 1;
    const int m0  = blockIdx.x * 128;
    const int n0g = blockIdx.y * 128;

    f32x4 acc[4][4] = {};

    const int srow = w * 32 + (lane >> 2);
    const int scol = (lane & 3) * 8;
    const u16* ag0 = xb + (size_t)(m0 + srow) * 2048 + scol;
    const u16* bg0 = Wt + (size_t)(n0g + srow) * 2048 + scol;

    #define STAGE_QKV(sel, kb) do { \
        g2l16(ag0 + (kb),             &Al[sel][w * 32][0]); \
        g2l16(ag0 + (kb) + 16 * 2048, &Al[sel][w * 32 + 16][0]); \
        g2l16(bg0 + (kb),             &Bl[sel][w * 32][0]); \
        g2l16(bg0 + (kb) + 16 * 2048, &Bl[sel][w * 32 + 16][0]); } while (0)

    STAGE_QKV(0, 0);
    __syncthreads();
    for (int kb = 0; kb < 2048; kb += 64) {
        STAGE_QKV(1, kb + 32);                       // next tile in flight during compute
        gemm_step(Al[0], Bl[0], lane, wm, wn, acc);
        __syncthreads();
        if (kb + 64 < 2048) STAGE_QKV(0, kb + 64);
        gemm_step(Al[1], Bl[1], lane, wm, wn, acc);
        __syncthreads();
    }
    #undef STAGE_QKV

    const int r0 = (lane >> 4) * 4;
    const int c0 = lane & 15;
    const int colbase = n0g + wn * 64;
    const bool isV = (n0g >= 2560);
    const bool isQ = (n0g < 2048);

    #pragma unroll
    for (int m = 0; m < 4; ++m) {
        #pragma unroll
        for (int r = 0; r < 4; ++r) {
            int rw = m0 + wm * 64 + m * 16 + r0 + r;
            int b = rw >> 11, t = rw & 2047;
            if (!isV) {
                #pragma unroll
                for (int np = 0; np < 2; ++np) {
                    int dp = np * 16 + c0;
                    float2 cs = tab[t * 32 + dp];
                    float x1 = acc[m][np][r];
                    float x2 = acc[m][np + 2][r];
                    float lo = x1 * cs.x - x2 * cs.y;
                    float hi = x2 * cs.x + x1 * cs.y;
                    if (isQ) {
                        int h = colbase >> 6;
                        size_t base = (((size_t)b * 32 + h) * 2048 + t) * 64 + dp;
                        Qb[base]      = f2bf(lo);
                        Qb[base + 32] = f2bf(hi);
                    } else {
                        int hk = (colbase - 2048) >> 6;
                        size_t base = (((size_t)b * 8 + hk) * 2048 + t) * 64 + dp;
                        Kb[base]      = f2bf(lo);
                        Kb[base + 32] = f2bf(hi);
                    }
                }
            } else {
                #pragma unroll
                for (int n = 0; n < 4; ++n) {
                    int c2 = colbase + n * 16 + c0 - 2560;
                    int hk = c2 >> 6, d = c2 & 63;
                    Vb[(((size_t)b * 8 + hk) * 2048 + t) * 64 + d] = f2bf(acc[m][n][r]);
                }
            }
        }
    }
}

// ---------------- V transpose: (b,hk,t,d) -> (b,hk,d,t) ----------------
__global__ __launch_bounds__(256)
void vtrans(const u16* __restrict__ Vb, u16* __restrict__ Vt)
{
    __shared__ __align__(16) u16 tile[64][68];
    const int tid = threadIdx.x;
    const int t0 = blockIdx.x * 64;
    const size_t base = (size_t)blockIdx.y * 2048 * 64;
    {
        int r = tid >> 2, c0 = (tid & 3) * 16;
        const u16* src = Vb + base + (size_t)(t0 + r) * 64 + c0;
        *(u16x8*)&tile[r][c0]     = *(const u16x8*)src;
        *(u16x8*)&tile[r][c0 + 8] = *(const u16x8*)(src + 8);
    }
    __syncthreads();
    {
        int d = tid >> 2, j0 = (tid & 3) * 16;
        u16x8 o0, o1;
        #pragma unroll
        for (int i = 0; i < 8; ++i) o0[i] = tile[j0 + i][d];
        #pragma unroll
        for (int i = 0; i < 8; ++i) o1[i] = tile[j0 + 8 + i][d];
        u16* dst = Vt + base + (size_t)d * 2048 + t0 + j0;
        *(u16x8*)dst       = o0;
        *(u16x8*)(dst + 8) = o1;
    }
}

// ---------------- Flash attention: swapped QK^T, log2-domain, XOR-swizzled LDS ----------------
__global__ __launch_bounds__(256)
void attn_kernel(const u16* __restrict__ Qb, const u16* __restrict__ Kb,
                 const u16* __restrict__ Vt, u16* __restrict__ AO)
{
    __shared__ __align__(16) u16 Kl[64][64];    // XOR-swizzled 16B chunks
    __shared__ __align__(16) u16 Vl[64][64];    // Vl[d][j], swizzled
    __shared__ __align__(16) u16 Pl[4][16][64]; // per-wave [q][k], swizzled

    const int tid = threadIdx.x;
    const int lane = tid & 63;
    const int w = tid >> 6;
    const int q = lane & 15;
    const int hq = lane >> 4;
    const int q0 = blockIdx.x * 64;
    const int bh = blockIdx.y;
    const int b = bh >> 5, h = bh & 31;
    const int hk = h >> 2;
    const size_t qbase  = (size_t)bh * 2048 * 64;
    const size_t kvbase = ((size_t)b * 8 + hk) * 2048 * 64;

    const int sj = tid >> 2;
    const int sd = (tid & 3) * 16;
    const int sc0 = (tid & 3) * 2;
    const int sw0 = ((sc0    ) ^ (sj & 7)) << 3;
    const int sw1 = ((sc0 + 1) ^ (sj & 7)) << 3;
    const int ca0 = ((hq    ) ^ (q & 7)) << 3;
    const int ca1 = ((hq + 4) ^ (q & 7)) << 3;

    bf16x8 qf0, qf1;
    {
        const u16* qp = Qb + qbase + (size_t)(q0 + w * 16 + q) * 64 + hq * 8;
        qf0 = ld_bf8(qp);
        qf1 = ld_bf8(qp + 32);
    }

    float mrun = -1e20f, lrun = 0.f;
    f32x4 o[4] = {};

    int kbeg = q0 - (WINDOW - 1);
    if (kbeg < 0) kbeg = 0;
    kbeg &= ~63;
    const int kend = q0 + 64;

    const int wrow_min = q0 + w * 16;
    const int wrow_max = wrow_min + 15;
    const int iq = wrow_min + q;

    u16x8 kr0, kr1, vr0, vr1;
    {
        const u16* kg = Kb + kvbase + (size_t)(kbeg + sj) * 64 + sd;
        kr0 = *(const u16x8*)kg;
        kr1 = *(const u16x8*)(kg + 8);
        const u16* vg = Vt + kvbase + (size_t)sj * 2048 + kbeg + sd;
        vr0 = *(const u16x8*)vg;
        vr1 = *(const u16x8*)(vg + 8);
    }
    *(u16x8*)&Kl[sj][sw0] = kr0;
    *(u16x8*)&Kl[sj][sw1] = kr1;
    *(u16x8*)&Vl[sj][sw0] = vr0;
    *(u16x8*)&Vl[sj][sw1] = vr1;
    __syncthreads();

    for (int k0 = kbeg; k0 < kend; k0 += 64) {
        const bool has_next = (k0 + 64 < kend);
        if (has_next) {
            const u16* kg = Kb + kvbase + (size_t)(k0 + 64 + sj) * 64 + sd;
            kr0 = *(const u16x8*)kg;
            kr1 = *(const u16x8*)(kg + 8);
            const u16* vg = Vt + kvbase + (size_t)sj * 2048 + k0 + 64 + sd;
            vr0 = *(const u16x8*)vg;
            vr1 = *(const u16x8*)(vg + 8);
        }

        bool active = (k0 <= wrow_max) && (k0 + 63 >= wrow_min - (WINDOW - 1));
        if (active) {
            f32x4 s[4];
            #pragma unroll
            for (int nf = 0; nf < 4; ++nf) {
                bf16x8 kb0 = ld_bf8(&Kl[nf * 16 + q][ca0]);
                bf16x8 kb1 = ld_bf8(&Kl[nf * 16 + q][ca1]);
                f32x4 a = {};
                a = __builtin_amdgcn_mfma_f32_16x16x32_bf16(kb0, qf0, a, 0, 0, 0);
                a = __builtin_amdgcn_mfma_f32_16x16x32_bf16(kb1, qf1, a, 0, 0, 0);
                s[nf] = a;
            }
            bool need_causal = (k0 + 63 > wrow_min);
            bool need_window = (wrow_max - k0) >= WINDOW;
            if (need_causal || need_window) {
                #pragma unroll
                for (int nf = 0; nf < 4; ++nf) {
                    #pragma unroll
                    for (int r = 0; r < 4; ++r) {
                        int j = k0 + nf * 16 + hq * 4 + r;
                        bool ok = (j <= iq) && (iq - j < WINDOW);
                        if (!ok) s[nf][r] = -1e30f;
                    }
                }
            }
            float tmax = s[0][0];
            #pragma unroll
            for (int nf = 0; nf < 4; ++nf)
                #pragma unroll
                for (int r = 0; r < 4; ++r) tmax = fmaxf(tmax, s[nf][r]);
            tmax = fmaxf(tmax, __shfl_xor(tmax, 16));
            tmax = fmaxf(tmax, __shfl_xor(tmax, 32));

            bool skip = __all(tmax <= mrun + 11.5f);
            float mnew = skip ? mrun : fmaxf(mrun, tmax);

            float tsum = 0.f;
            #pragma unroll
            for (int nf = 0; nf < 4; ++nf) {
                float p0 = exp2f_raw(s[nf][0] - mnew);
                float p1 = exp2f_raw(s[nf][1] - mnew);
                float p2 = exp2f_raw(s[nf][2] - mnew);
                float p3 = exp2f_raw(s[nf][3] - mnew);
                tsum += (p0 + p1) + (p2 + p3);
                u32x2 pw = { cvt_pk_bf16(p0, p1), cvt_pk_bf16(p2, p3) };
                int cpw = (((2 * nf + (hq >> 1)) ^ (q & 7)) << 3) + ((hq & 1) << 2);
                *(u32x2*)&Pl[w][q][cpw] = pw;
            }
            tsum += __shfl_xor(tsum, 16);
            tsum += __shfl_xor(tsum, 32);

            if (skip) {
                lrun += tsum;
            } else {
                float sc = exp2f_raw(mrun - mnew);
                mrun = mnew;
                lrun = lrun * sc + tsum;
                float osc[4];
                #pragma unroll
                for (int r = 0; r < 4; ++r)
                    osc[r] = __shfl(sc, (lane & 48) + hq * 4 + r);
                #pragma unroll
                for (int nf = 0; nf < 4; ++nf)
                    #pragma unroll
                    for (int r = 0; r < 4; ++r)
                        o[nf][r] *= osc[r];
            }

            bf16x8 pa0 = ld_bf8(&Pl[w][q][ca0]);
            bf16x8 pa1 = ld_bf8(&Pl[w][q][ca1]);
            #pragma unroll
            for (int nf = 0; nf < 4; ++nf) {
                bf16x8 vb0 = ld_bf8(&Vl[nf * 16 + q][ca0]);
                bf16x8 vb1 = ld_bf8(&Vl[nf * 16 + q][ca1]);
                o[nf] = __builtin_amdgcn_mfma_f32_16x16x32_bf16(pa0, vb0, o[nf], 0, 0, 0);
                o[nf] = __builtin_amdgcn_mfma_f32_16x16x32_bf16(pa1, vb1, o[nf], 0, 0, 0);
            }
        }
        __syncthreads();
        if (has_next) {
            *(u16x8*)&Kl[sj][sw0] = kr0;
            *(u16x8*)&Kl[sj][sw1] = kr1;
            *(u16x8*)&Vl[sj][sw0] = vr0;
            *(u16x8*)&Vl[sj][sw1] = vr1;
        }
        __syncthreads();
    }

    float linv_own = 1.f / lrun;
    float linv[4];
    #pragma unroll
    for (int r = 0; r < 4; ++r)
        linv[r] = __shfl(linv_own, (lane & 48) + hq * 4 + r);
    #pragma unroll
    for (int nf = 0; nf < 4; ++nf) {
        #pragma unroll
        for (int r = 0; r < 4; ++r) {
            int i = q0 + w * 16 + hq * 4 + r;
            int d = nf * 16 + q;
            AO[((size_t)b * 2048 + i) * 2048 + h * 64 + d] = f2bf(o[nf][r] * linv[r]);
        }
    }
}

// ---------------- Output projection: 2-phase dbuf, natural grid ----------------
__global__ __launch_bounds__(256)
void out_gemm(const u16* __restrict__ A, const u16* __restrict__ Wt, float* __restrict__ C)
{
    __shared__ __align__(16) u16 Al[2][128][32];
    __shared__ __align__(16) u16 Bl[2][128][32];
    const int tid = threadIdx.x;
    const int lane = tid & 63;
    const int w = tid >> 6;
    const int wm = w >> 1, wn = w & 1;
    const int m0 = blockIdx.x * 128;
    const int n0 = blockIdx.y * 128;

    f32x4 acc[4][4] = {};

    const int srow = w * 32 + (lane >> 2);
    const int scol = (lane & 3) * 8;
    const u16* ag0 = A  + (size_t)(m0 + srow) * 2048 + scol;
    const u16* bg0 = Wt + (size_t)(n0 + srow) * 2048 + scol;

    #define STAGE_O(sel, kb) do { \
        g2l16(ag0 + (kb),             &Al[sel][w * 32][0]); \
        g2l16(ag0 + (kb) + 16 * 2048, &Al[sel][w * 32 + 16][0]); \
        g2l16(bg0 + (kb),             &Bl[sel][w * 32][0]); \
        g2l16(bg0 + (kb) + 16 * 2048, &Bl[sel][w * 32 + 16][0]); } while (0)

    STAGE_O(0, 0);
    __syncthreads();
    for (int kb = 0; kb < 2048; kb += 64) {
        STAGE_O(1, kb + 32);
        gemm_step(Al[0], Bl[0], lane, wm, wn, acc);
        __syncthreads();
        if (kb + 64 < 2048) STAGE_O(0, kb + 64);
        gemm_step(Al[1], Bl[1], lane, wm, wn, acc);
        __syncthreads();
    }
    #undef STAGE_O

    const int r0 = (lane >> 4) * 4;
    const int c0 = lane & 15;
    #pragma unroll
    for (int m = 0; m < 4; ++m) {
        #pragma unroll
        for (int n = 0; n < 4; ++n) {
            #pragma unroll
            for (int r = 0; r < 4; ++r) {
                int rw = m0 + wm * 64 + m * 16 + r0 + r;
                int col = n0 + wn * 64 + n * 16 + c0;
                C[(size_t)rw * 2048 + col] = acc[m][n][r];
            }
        }
    }
}

extern "C" void kernel_launch(void* const* d_in, const int* in_sizes, int n_in,
                              void* d_out, int out_size, void* d_ws, size_t ws_size,
                              hipStream_t stream)
{
    const float* x  = (const float*)d_in[0];
    const float* Wq = (const float*)d_in[1];
    const float* Wk = (const float*)d_in[2];
    const float* Wv = (const float*)d_in[3];
    const float* Wo = (const float*)d_in[4];
    float* out = (float*)d_out;

    u16* Qb    = (u16*)d_ws;                              //  8,388,608
    u16* Kb    = Qb    + (size_t)8388608;                 //  2,097,152
    u16* Vb    = Kb    + (size_t)2097152;                 //  2,097,152
    u16* Vt    = Vb    + (size_t)2097152;                 //  2,097,152
    u16* AO    = Vt    + (size_t)2097152;                 //  8,388,608
    u16* xb    = AO    + (size_t)8388608;                 //  8,388,608
    u16* WqkvT = xb    + (size_t)8388608;                 //  6,291,456  [3072][2048]
    u16* WoT   = WqkvT + (size_t)6291456;                 //  4,194,304  [2048][2048]
    float2* tab = (float2*)(WoT + (size_t)4194304);       //  512KB

    rope_tab_kernel<<<256, 256, 0, stream>>>(tab);
    convert_x<<<4096, 256, 0, stream>>>(x, xb);
    trans_conv_all<<<dim3(32, 32, 4), 256, 0, stream>>>(Wq, Wk, Wv, Wo, WqkvT, WoT);

    qkv_gemm<<<dim3(32, 24), 256, 0, stream>>>(xb, WqkvT, tab, Qb, Kb, Vb);
    vtrans<<<dim3(32, 16), 256, 0, stream>>>(Vb, Vt);
    attn_kernel<<<dim3(32, 64), 256, 0, stream>>>(Qb, Kb, Vt, AO);
    out_gemm<<<dim3(32, 16), 256, 0, stream>>>(AO, WoT, out);
}

// Round 9
// 204.446 us; speedup vs baseline: 1.2202x; 1.1542x over previous
//
#include <hip/hip_runtime.h>

typedef unsigned short u16;
typedef __attribute__((ext_vector_type(8))) unsigned short u16x8;
typedef __attribute__((ext_vector_type(2))) unsigned int u32x2;
typedef __attribute__((ext_vector_type(8))) __bf16 bf16x8;
typedef __attribute__((ext_vector_type(4))) float f32x4;

#define T_SEQ 2048
#define WINDOW 1024
// 0.125 * log2(e)
#define QSCALE 0.18033688011112042f

static __device__ __forceinline__ u16 f2bf(float f) {
    unsigned int u = __float_as_uint(f);
    u += 0x7fffu + ((u >> 16) & 1u);
    return (u16)(u >> 16);
}
static __device__ __forceinline__ float bf2f(u16 h) {
    return __uint_as_float(((unsigned int)h) << 16);
}
static __device__ __forceinline__ bf16x8 ld_bf8(const u16* p) {
    return __builtin_bit_cast(bf16x8, *(const u16x8*)p);
}
static __device__ __forceinline__ unsigned int cvt_pk_bf16(float lo, float hi) {
    unsigned int r;
    asm("v_cvt_pk_bf16_f32 %0, %1, %2" : "=v"(r) : "v"(lo), "v"(hi));
    return r;
}
static __device__ __forceinline__ float exp2f_raw(float x) {
#if __has_builtin(__builtin_amdgcn_exp2f)
    return __builtin_amdgcn_exp2f(x);
#else
    return exp2f(x);
#endif
}
// async global -> LDS, 16B per lane (wave-uniform LDS base + lane*16)
static __device__ __forceinline__ void g2l16(const void* g, void* l) {
    __builtin_amdgcn_global_load_lds(
        (const __attribute__((address_space(1))) void*)g,
        (__attribute__((address_space(3))) void*)l, 16, 0, 0);
}

// ---------------- RoPE cos/sin table: float2[2048][32] ----------------
__global__ __launch_bounds__(256)
void rope_tab_kernel(float2* __restrict__ tab)
{
    int idx = blockIdx.x * 256 + threadIdx.x;   // 65536
    int t = idx >> 5, dp = idx & 31;
    float inv_freq = __expf(-dp * 0.28782313662425574f); // ln(10000)/32
    float ang = (float)t * inv_freq;
    float s, c;
    sincosf(ang, &s, &c);
    tab[idx] = make_float2(c, s);
}

// ---------------- x fp32 -> bf16 (same layout) ----------------
__global__ __launch_bounds__(256)
void convert_x(const float* __restrict__ src, u16* __restrict__ dst)
{
    int i8 = blockIdx.x * 256 + threadIdx.x;
    size_t base = (size_t)i8 * 8;
    float4 a = *(const float4*)(src + base);
    float4 b = *(const float4*)(src + base + 4);
    u16x8 o = { f2bf(a.x), f2bf(a.y), f2bf(a.z), f2bf(a.w),
                f2bf(b.x), f2bf(b.y), f2bf(b.z), f2bf(b.w) };
    *(u16x8*)(dst + base) = o;
}

// ---------------- all W fp32 [2048][N] -> bf16 transposed [N][2048], scaled ----------------
__global__ __launch_bounds__(256)
void trans_conv_all(const float* __restrict__ Wq, const float* __restrict__ Wk,
                    const float* __restrict__ Wv, const float* __restrict__ Wo,
                    u16* __restrict__ WqkvT, u16* __restrict__ WoT)
{
    __shared__ __align__(16) u16 tile[64][72];
    const int z = blockIdx.z;
    const float* src; int N; float scale; u16* dst;
    if (z == 0)      { src = Wq; N = 2048; scale = QSCALE; dst = WqkvT; }
    else if (z == 1) { src = Wk; N = 512;  scale = 1.f;    dst = WqkvT + (size_t)2048 * 2048; }
    else if (z == 2) { src = Wv; N = 512;  scale = 1.f;    dst = WqkvT + (size_t)2560 * 2048; }
    else             { src = Wo; N = 2048; scale = 1.f;    dst = WoT; }
    if ((int)blockIdx.y * 64 >= N) return;

    const int tid = threadIdx.x;
    const int k0 = blockIdx.x * 64;
    const int n0 = blockIdx.y * 64;
    {
        int r = tid >> 2, c0 = (tid & 3) * 16;
        const float* sp = src + (size_t)(k0 + r) * N + n0 + c0;
        float4 v0 = *(const float4*)(sp + 0);
        float4 v1 = *(const float4*)(sp + 4);
        float4 v2 = *(const float4*)(sp + 8);
        float4 v3 = *(const float4*)(sp + 12);
        u16x8 s0 = { f2bf(v0.x * scale), f2bf(v0.y * scale), f2bf(v0.z * scale), f2bf(v0.w * scale),
                     f2bf(v1.x * scale), f2bf(v1.y * scale), f2bf(v1.z * scale), f2bf(v1.w * scale) };
        u16x8 s1 = { f2bf(v2.x * scale), f2bf(v2.y * scale), f2bf(v2.z * scale), f2bf(v2.w * scale),
                     f2bf(v3.x * scale), f2bf(v3.y * scale), f2bf(v3.z * scale), f2bf(v3.w * scale) };
        *(u16x8*)&tile[r][c0]     = s0;
        *(u16x8*)&tile[r][c0 + 8] = s1;
    }
    __syncthreads();
    {
        int n = tid >> 2, j0 = (tid & 3) * 16;
        u16x8 o0, o1;
        #pragma unroll
        for (int i = 0; i < 8; ++i) o0[i] = tile[j0 + i][n];
        #pragma unroll
        for (int i = 0; i < 8; ++i) o1[i] = tile[j0 + 8 + i][n];
        u16* dp = dst + (size_t)(n0 + n) * 2048 + k0 + j0;
        *(u16x8*)dp       = o0;
        *(u16x8*)(dp + 8) = o1;
    }
}

// ================= GEMM core: 128 threads (2 waves), block 128x128, =================
// ================= per-wave 128x64, BK=64, XOR-swizzled conflict-free LDS ==========
// LDS [128][64] u16: phys chunk (16B) c holds logical chunk c^(row&7).
// Staged via g2l16 with inverse-swizzled per-lane GLOBAL source (rule #21).
// Read: logical chunk q of row r at phys chunk q^(r&7)  -> bank-conflict-free.
struct GemmAcc { f32x4 a[8][4]; };

__device__ __forceinline__ void gemm_core_128(const u16* __restrict__ Ag,  // + m0 row base
                                              const u16* __restrict__ Bg,  // + n0 row base
                                              u16 (*Al)[64], u16 (*Bl)[64],
                                              int lane, int w, GemmAcc& acc)
{
    const int r8 = lane >> 3;             // row-within-8 of staging
    const int cs = (lane & 7) ^ r8;       // inverse-swizzled source chunk
    const u16* ag = Ag + (size_t)(w * 64 + r8) * 2048 + cs * 8;
    const u16* bg = Bg + (size_t)(w * 64 + r8) * 2048 + cs * 8;
    const int fr = lane & 15;
    const int hq = lane >> 4;

    for (int kb = 0; kb < 2048; kb += 64) {
        #pragma unroll
        for (int ii = 0; ii < 8; ++ii)
            g2l16(ag + (size_t)(ii * 8) * 2048 + kb, &Al[w * 64 + ii * 8][0]);
        #pragma unroll
        for (int ii = 0; ii < 8; ++ii)
            g2l16(bg + (size_t)(ii * 8) * 2048 + kb, &Bl[w * 64 + ii * 8][0]);
        __syncthreads();

        #pragma unroll
        for (int kk = 0; kk < 2; ++kk) {
            bf16x8 af[8], bfn[4];
            #pragma unroll
            for (int m = 0; m < 8; ++m) {
                int row = m * 16 + fr;
                int pc = (kk * 4 + hq) ^ (row & 7);
                af[m] = ld_bf8(&Al[row][pc * 8]);
            }
            #pragma unroll
            for (int n = 0; n < 4; ++n) {
                int row = w * 64 + n * 16 + fr;
                int pc = (kk * 4 + hq) ^ (row & 7);
                bfn[n] = ld_bf8(&Bl[row][pc * 8]);
            }
            #pragma unroll
            for (int m = 0; m < 8; ++m)
                #pragma unroll
                for (int n = 0; n < 4; ++n)
                    acc.a[m][n] = __builtin_amdgcn_mfma_f32_16x16x32_bf16(af[m], bfn[n], acc.a[m][n], 0, 0, 0);
        }
        __syncthreads();
    }
}

// ---------------- QKV GEMM + fused RoPE epilogue ----------------
__global__ __launch_bounds__(128, 2)
void qkv_gemm(const u16* __restrict__ xb, const u16* __restrict__ Wt,
              const float2* __restrict__ tab,
              u16* __restrict__ Qb, u16* __restrict__ Kb, u16* __restrict__ Vb)
{
    __shared__ __align__(16) u16 Al[128][64];
    __shared__ __align__(16) u16 Bl[128][64];
    const int tid = threadIdx.x;
    const int lane = tid & 63;
    const int w = tid >> 6;
    const int m0  = blockIdx.x * 128;
    const int n0g = blockIdx.y * 128;

    GemmAcc acc = {};
    gemm_core_128(xb + (size_t)m0 * 2048, Wt + (size_t)n0g * 2048, Al, Bl, lane, w, acc);

    const int hq = lane >> 4;
    const int c0 = lane & 15;
    const int colbase = n0g + w * 64;          // multiple of 64
    const bool isV = (n0g >= 2560);
    const bool isQ = (n0g < 2048);

    #pragma unroll
    for (int m = 0; m < 8; ++m) {
        #pragma unroll
        for (int r = 0; r < 4; ++r) {
            int rw = m0 + m * 16 + hq * 4 + r;
            int b = rw >> 11, t = rw & 2047;
            if (!isV) {
                #pragma unroll
                for (int np = 0; np < 2; ++np) {
                    int dp = np * 16 + c0;
                    float2 cs = tab[t * 32 + dp];
                    float x1 = acc.a[m][np][r];
                    float x2 = acc.a[m][np + 2][r];
                    float lo = x1 * cs.x - x2 * cs.y;
                    float hi = x2 * cs.x + x1 * cs.y;
                    if (isQ) {
                        int h = colbase >> 6;
                        size_t base = (((size_t)b * 32 + h) * 2048 + t) * 64 + dp;
                        Qb[base]      = f2bf(lo);
                        Qb[base + 32] = f2bf(hi);
                    } else {
                        int hk = (colbase - 2048) >> 6;
                        size_t base = (((size_t)b * 8 + hk) * 2048 + t) * 64 + dp;
                        Kb[base]      = f2bf(lo);
                        Kb[base + 32] = f2bf(hi);
                    }
                }
            } else {
                #pragma unroll
                for (int n = 0; n < 4; ++n) {
                    int c2 = colbase + n * 16 + c0 - 2560;
                    int hk = c2 >> 6, d = c2 & 63;
                    Vb[(((size_t)b * 8 + hk) * 2048 + t) * 64 + d] = f2bf(acc.a[m][n][r]);
                }
            }
        }
    }
}

// ---------------- Output projection ----------------
__global__ __launch_bounds__(128, 2)
void out_gemm(const u16* __restrict__ A, const u16* __restrict__ Wt, float* __restrict__ C)
{
    __shared__ __align__(16) u16 Al[128][64];
    __shared__ __align__(16) u16 Bl[128][64];
    const int tid = threadIdx.x;
    const int lane = tid & 63;
    const int w = tid >> 6;
    const int m0 = blockIdx.x * 128;
    const int n0 = blockIdx.y * 128;

    GemmAcc acc = {};
    gemm_core_128(A + (size_t)m0 * 2048, Wt + (size_t)n0 * 2048, Al, Bl, lane, w, acc);

    const int hq = lane >> 4;
    const int c0 = lane & 15;
    #pragma unroll
    for (int m = 0; m < 8; ++m) {
        #pragma unroll
        for (int n = 0; n < 4; ++n) {
            #pragma unroll
            for (int r = 0; r < 4; ++r) {
                int rw = m0 + m * 16 + hq * 4 + r;
                int col = n0 + w * 64 + n * 16 + c0;
                C[(size_t)rw * 2048 + col] = acc.a[m][n][r];
            }
        }
    }
}

// ---------------- V transpose: (b,hk,t,d) -> (b,hk,d,t) ----------------
__global__ __launch_bounds__(256)
void vtrans(const u16* __restrict__ Vb, u16* __restrict__ Vt)
{
    __shared__ __align__(16) u16 tile[64][68];
    const int tid = threadIdx.x;
    const int t0 = blockIdx.x * 64;
    const size_t base = (size_t)blockIdx.y * 2048 * 64;
    {
        int r = tid >> 2, c0 = (tid & 3) * 16;
        const u16* src = Vb + base + (size_t)(t0 + r) * 64 + c0;
        *(u16x8*)&tile[r][c0]     = *(const u16x8*)src;
        *(u16x8*)&tile[r][c0 + 8] = *(const u16x8*)(src + 8);
    }
    __syncthreads();
    {
        int d = tid >> 2, j0 = (tid & 3) * 16;
        u16x8 o0, o1;
        #pragma unroll
        for (int i = 0; i < 8; ++i) o0[i] = tile[j0 + i][d];
        #pragma unroll
        for (int i = 0; i < 8; ++i) o1[i] = tile[j0 + 8 + i][d];
        u16* dst = Vt + base + (size_t)d * 2048 + t0 + j0;
        *(u16x8*)dst       = o0;
        *(u16x8*)(dst + 8) = o1;
    }
}

// ---------------- Flash attention: swapped QK^T, log2-domain, XOR-swizzled LDS ----------------
__global__ __launch_bounds__(256)
void attn_kernel(const u16* __restrict__ Qb, const u16* __restrict__ Kb,
                 const u16* __restrict__ Vt, u16* __restrict__ AO)
{
    __shared__ __align__(16) u16 Kl[64][64];    // XOR-swizzled 16B chunks
    __shared__ __align__(16) u16 Vl[64][64];    // Vl[d][j], swizzled
    __shared__ __align__(16) u16 Pl[4][16][64]; // per-wave [q][k], swizzled

    const int tid = threadIdx.x;
    const int lane = tid & 63;
    const int w = tid >> 6;
    const int q = lane & 15;
    const int hq = lane >> 4;
    const int q0 = blockIdx.x * 64;
    const int bh = blockIdx.y;
    const int b = bh >> 5, h = bh & 31;
    const int hk = h >> 2;
    const size_t qbase  = (size_t)bh * 2048 * 64;
    const size_t kvbase = ((size_t)b * 8 + hk) * 2048 * 64;

    const int sj = tid >> 2;
    const int sd = (tid & 3) * 16;
    const int sc0 = (tid & 3) * 2;
    const int sw0 = ((sc0    ) ^ (sj & 7)) << 3;
    const int sw1 = ((sc0 + 1) ^ (sj & 7)) << 3;
    const int ca0 = ((hq    ) ^ (q & 7)) << 3;
    const int ca1 = ((hq + 4) ^ (q & 7)) << 3;

    bf16x8 qf0, qf1;
    {
        const u16* qp = Qb + qbase + (size_t)(q0 + w * 16 + q) * 64 + hq * 8;
        qf0 = ld_bf8(qp);
        qf1 = ld_bf8(qp + 32);
    }

    float mrun = -1e20f, lrun = 0.f;
    f32x4 o[4] = {};

    int kbeg = q0 - (WINDOW - 1);
    if (kbeg < 0) kbeg = 0;
    kbeg &= ~63;
    const int kend = q0 + 64;

    const int wrow_min = q0 + w * 16;
    const int wrow_max = wrow_min + 15;
    const int iq = wrow_min + q;

    u16x8 kr0, kr1, vr0, vr1;
    {
        const u16* kg = Kb + kvbase + (size_t)(kbeg + sj) * 64 + sd;
        kr0 = *(const u16x8*)kg;
        kr1 = *(const u16x8*)(kg + 8);
        const u16* vg = Vt + kvbase + (size_t)sj * 2048 + kbeg + sd;
        vr0 = *(const u16x8*)vg;
        vr1 = *(const u16x8*)(vg + 8);
    }
    *(u16x8*)&Kl[sj][sw0] = kr0;
    *(u16x8*)&Kl[sj][sw1] = kr1;
    *(u16x8*)&Vl[sj][sw0] = vr0;
    *(u16x8*)&Vl[sj][sw1] = vr1;
    __syncthreads();

    for (int k0 = kbeg; k0 < kend; k0 += 64) {
        const bool has_next = (k0 + 64 < kend);
        if (has_next) {
            const u16* kg = Kb + kvbase + (size_t)(k0 + 64 + sj) * 64 + sd;
            kr0 = *(const u16x8*)kg;
            kr1 = *(const u16x8*)(kg + 8);
            const u16* vg = Vt + kvbase + (size_t)sj * 2048 + k0 + 64 + sd;
            vr0 = *(const u16x8*)vg;
            vr1 = *(const u16x8*)(vg + 8);
        }

        bool active = (k0 <= wrow_max) && (k0 + 63 >= wrow_min - (WINDOW - 1));
        if (active) {
            f32x4 s[4];
            #pragma unroll
            for (int nf = 0; nf < 4; ++nf) {
                bf16x8 kb0 = ld_bf8(&Kl[nf * 16 + q][ca0]);
                bf16x8 kb1 = ld_bf8(&Kl[nf * 16 + q][ca1]);
                f32x4 a = {};
                a = __builtin_amdgcn_mfma_f32_16x16x32_bf16(kb0, qf0, a, 0, 0, 0);
                a = __builtin_amdgcn_mfma_f32_16x16x32_bf16(kb1, qf1, a, 0, 0, 0);
                s[nf] = a;
            }
            bool need_causal = (k0 + 63 > wrow_min);
            bool need_window = (wrow_max - k0) >= WINDOW;
            if (need_causal || need_window) {
                #pragma unroll
                for (int nf = 0; nf < 4; ++nf) {
                    #pragma unroll
                    for (int r = 0; r < 4; ++r) {
                        int j = k0 + nf * 16 + hq * 4 + r;
                        bool ok = (j <= iq) && (iq - j < WINDOW);
                        if (!ok) s[nf][r] = -1e30f;
                    }
                }
            }
            float tmax = s[0][0];
            #pragma unroll
            for (int nf = 0; nf < 4; ++nf)
                #pragma unroll
                for (int r = 0; r < 4; ++r) tmax = fmaxf(tmax, s[nf][r]);
            tmax = fmaxf(tmax, __shfl_xor(tmax, 16));
            tmax = fmaxf(tmax, __shfl_xor(tmax, 32));

            bool skip = __all(tmax <= mrun + 11.5f);
            float mnew = skip ? mrun : fmaxf(mrun, tmax);

            float tsum = 0.f;
            #pragma unroll
            for (int nf = 0; nf < 4; ++nf) {
                float p0 = exp2f_raw(s[nf][0] - mnew);
                float p1 = exp2f_raw(s[nf][1] - mnew);
                float p2 = exp2f_raw(s[nf][2] - mnew);
                float p3 = exp2f_raw(s[nf][3] - mnew);
                tsum += (p0 + p1) + (p2 + p3);
                u32x2 pw = { cvt_pk_bf16(p0, p1), cvt_pk_bf16(p2, p3) };
                int cpw = (((2 * nf + (hq >> 1)) ^ (q & 7)) << 3) + ((hq & 1) << 2);
                *(u32x2*)&Pl[w][q][cpw] = pw;
            }
            tsum += __shfl_xor(tsum, 16);
            tsum += __shfl_xor(tsum, 32);

            if (skip) {
                lrun += tsum;
            } else {
                float sc = exp2f_raw(mrun - mnew);
                mrun = mnew;
                lrun = lrun * sc + tsum;
                float osc[4];
                #pragma unroll
                for (int r = 0; r < 4; ++r)
                    osc[r] = __shfl(sc, (lane & 48) + hq * 4 + r);
                #pragma unroll
                for (int nf = 0; nf < 4; ++nf)
                    #pragma unroll
                    for (int r = 0; r < 4; ++r)
                        o[nf][r] *= osc[r];
            }

            bf16x8 pa0 = ld_bf8(&Pl[w][q][ca0]);
            bf16x8 pa1 = ld_bf8(&Pl[w][q][ca1]);
            #pragma unroll
            for (int nf = 0; nf < 4; ++nf) {
                bf16x8 vb0 = ld_bf8(&Vl[nf * 16 + q][ca0]);
                bf16x8 vb1 = ld_bf8(&Vl[nf * 16 + q][ca1]);
                o[nf] = __builtin_amdgcn_mfma_f32_16x16x32_bf16(pa0, vb0, o[nf], 0, 0, 0);
                o[nf] = __builtin_amdgcn_mfma_f32_16x16x32_bf16(pa1, vb1, o[nf], 0, 0, 0);
            }
        }
        __syncthreads();
        if (has_next) {
            *(u16x8*)&Kl[sj][sw0] = kr0;
            *(u16x8*)&Kl[sj][sw1] = kr1;
            *(u16x8*)&Vl[sj][sw0] = vr0;
            *(u16x8*)&Vl[sj][sw1] = vr1;
        }
        __syncthreads();
    }

    float linv_own = 1.f / lrun;
    float linv[4];
    #pragma unroll
    for (int r = 0; r < 4; ++r)
        linv[r] = __shfl(linv_own, (lane & 48) + hq * 4 + r);
    #pragma unroll
    for (int nf = 0; nf < 4; ++nf) {
        #pragma unroll
        for (int r = 0; r < 4; ++r) {
            int i = q0 + w * 16 + hq * 4 + r;
            int d = nf * 16 + q;
            AO[((size_t)b * 2048 + i) * 2048 + h * 64 + d] = f2bf(o[nf][r] * linv[r]);
        }
    }
}

extern "C" void kernel_launch(void* const* d_in, const int* in_sizes, int n_in,
                              void* d_out, int out_size, void* d_ws, size_t ws_size,
                              hipStream_t stream)
{
    const float* x  = (const float*)d_in[0];
    const float* Wq = (const float*)d_in[1];
    const float* Wk = (const float*)d_in[2];
    const float* Wv = (const float*)d_in[3];
    const float* Wo = (const float*)d_in[4];
    float* out = (float*)d_out;

    u16* Qb    = (u16*)d_ws;                              //  8,388,608
    u16* Kb    = Qb    + (size_t)8388608;                 //  2,097,152
    u16* Vb    = Kb    + (size_t)2097152;                 //  2,097,152
    u16* Vt    = Vb    + (size_t)2097152;                 //  2,097,152
    u16* AO    = Vt    + (size_t)2097152;                 //  8,388,608
    u16* xb    = AO    + (size_t)8388608;                 //  8,388,608
    u16* WqkvT = xb    + (size_t)8388608;                 //  6,291,456  [3072][2048]
    u16* WoT   = WqkvT + (size_t)6291456;                 //  4,194,304  [2048][2048]
    float2* tab = (float2*)(WoT + (size_t)4194304);       //  512KB

    rope_tab_kernel<<<256, 256, 0, stream>>>(tab);
    convert_x<<<4096, 256, 0, stream>>>(x, xb);
    trans_conv_all<<<dim3(32, 32, 4), 256, 0, stream>>>(Wq, Wk, Wv, Wo, WqkvT, WoT);

    qkv_gemm<<<dim3(32, 24), 128, 0, stream>>>(xb, WqkvT, tab, Qb, Kb, Vb);
    vtrans<<<dim3(32, 16), 256, 0, stream>>>(Vb, Vt);
    attn_kernel<<<dim3(32, 64), 256, 0, stream>>>(Qb, Kb, Vt, AO);
    out_gemm<<<dim3(32, 16), 128, 0, stream>>>(AO, WoT, out);
}

// Round 10
// 198.445 us; speedup vs baseline: 1.2571x; 1.0302x over previous
//
#include <hip/hip_runtime.h>

typedef unsigned short u16;
typedef __attribute__((ext_vector_type(8))) unsigned short u16x8;
typedef __attribute__((ext_vector_type(2))) unsigned int u32x2;
typedef __attribute__((ext_vector_type(8))) __bf16 bf16x8;
typedef __attribute__((ext_vector_type(4))) float f32x4;

#define T_SEQ 2048
#define WINDOW 1024
// 0.125 * log2(e)
#define QSCALE 0.18033688011112042f

static __device__ __forceinline__ u16 f2bf(float f) {
    unsigned int u = __float_as_uint(f);
    u += 0x7fffu + ((u >> 16) & 1u);
    return (u16)(u >> 16);
}
static __device__ __forceinline__ float bf2f(u16 h) {
    return __uint_as_float(((unsigned int)h) << 16);
}
static __device__ __forceinline__ bf16x8 ld_bf8(const u16* p) {
    return __builtin_bit_cast(bf16x8, *(const u16x8*)p);
}
static __device__ __forceinline__ unsigned int cvt_pk_bf16(float lo, float hi) {
    unsigned int r;
    asm("v_cvt_pk_bf16_f32 %0, %1, %2" : "=v"(r) : "v"(lo), "v"(hi));
    return r;
}
static __device__ __forceinline__ float exp2f_raw(float x) {
#if __has_builtin(__builtin_amdgcn_exp2f)
    return __builtin_amdgcn_exp2f(x);
#else
    return exp2f(x);
#endif
}
// async global -> LDS, 16B per lane (wave-uniform LDS base + lane*16)
static __device__ __forceinline__ void g2l16(const void* g, void* l) {
    __builtin_amdgcn_global_load_lds(
        (const __attribute__((address_space(1))) void*)g,
        (__attribute__((address_space(3))) void*)l, 16, 0, 0);
}

// ---------------- RoPE cos/sin table: float2[2048][32] ----------------
__global__ __launch_bounds__(256)
void rope_tab_kernel(float2* __restrict__ tab)
{
    int idx = blockIdx.x * 256 + threadIdx.x;   // 65536
    int t = idx >> 5, dp = idx & 31;
    float inv_freq = __expf(-dp * 0.28782313662425574f); // ln(10000)/32
    float ang = (float)t * inv_freq;
    float s, c;
    sincosf(ang, &s, &c);
    tab[idx] = make_float2(c, s);
}

// ---------------- x fp32 -> bf16 (same layout) ----------------
__global__ __launch_bounds__(256)
void convert_x(const float* __restrict__ src, u16* __restrict__ dst)
{
    int i8 = blockIdx.x * 256 + threadIdx.x;
    size_t base = (size_t)i8 * 8;
    float4 a = *(const float4*)(src + base);
    float4 b = *(const float4*)(src + base + 4);
    u16x8 o = { f2bf(a.x), f2bf(a.y), f2bf(a.z), f2bf(a.w),
                f2bf(b.x), f2bf(b.y), f2bf(b.z), f2bf(b.w) };
    *(u16x8*)(dst + base) = o;
}

// ---------------- all W fp32 [2048][N] -> bf16 transposed [N][2048], scaled ----------------
__global__ __launch_bounds__(256)
void trans_conv_all(const float* __restrict__ Wq, const float* __restrict__ Wk,
                    const float* __restrict__ Wv, const float* __restrict__ Wo,
                    u16* __restrict__ WqkvT, u16* __restrict__ WoT)
{
    __shared__ __align__(16) u16 tile[64][72];
    const int z = blockIdx.z;
    const float* src; int N; float scale; u16* dst;
    if (z == 0)      { src = Wq; N = 2048; scale = QSCALE; dst = WqkvT; }
    else if (z == 1) { src = Wk; N = 512;  scale = 1.f;    dst = WqkvT + (size_t)2048 * 2048; }
    else if (z == 2) { src = Wv; N = 512;  scale = 1.f;    dst = WqkvT + (size_t)2560 * 2048; }
    else             { src = Wo; N = 2048; scale = 1.f;    dst = WoT; }
    if ((int)blockIdx.y * 64 >= N) return;

    const int tid = threadIdx.x;
    const int k0 = blockIdx.x * 64;
    const int n0 = blockIdx.y * 64;
    {
        int r = tid >> 2, c0 = (tid & 3) * 16;
        const float* sp = src + (size_t)(k0 + r) * N + n0 + c0;
        float4 v0 = *(const float4*)(sp + 0);
        float4 v1 = *(const float4*)(sp + 4);
        float4 v2 = *(const float4*)(sp + 8);
        float4 v3 = *(const float4*)(sp + 12);
        u16x8 s0 = { f2bf(v0.x * scale), f2bf(v0.y * scale), f2bf(v0.z * scale), f2bf(v0.w * scale),
                     f2bf(v1.x * scale), f2bf(v1.y * scale), f2bf(v1.z * scale), f2bf(v1.w * scale) };
        u16x8 s1 = { f2bf(v2.x * scale), f2bf(v2.y * scale), f2bf(v2.z * scale), f2bf(v2.w * scale),
                     f2bf(v3.x * scale), f2bf(v3.y * scale), f2bf(v3.z * scale), f2bf(v3.w * scale) };
        *(u16x8*)&tile[r][c0]     = s0;
        *(u16x8*)&tile[r][c0 + 8] = s1;
    }
    __syncthreads();
    {
        int n = tid >> 2, j0 = (tid & 3) * 16;
        u16x8 o0, o1;
        #pragma unroll
        for (int i = 0; i < 8; ++i) o0[i] = tile[j0 + i][n];
        #pragma unroll
        for (int i = 0; i < 8; ++i) o1[i] = tile[j0 + 8 + i][n];
        u16* dp = dst + (size_t)(n0 + n) * 2048 + k0 + j0;
        *(u16x8*)dp       = o0;
        *(u16x8*)(dp + 8) = o1;
    }
}

// ================= GEMM core: 128 threads (2 waves), block 128x128 =================
struct GemmAcc { f32x4 a[8][4]; };

__device__ __forceinline__ void gemm_core_128(const u16* __restrict__ Ag,
                                              const u16* __restrict__ Bg,
                                              u16 (*Al)[64], u16 (*Bl)[64],
                                              int lane, int w, GemmAcc& acc)
{
    const int r8 = lane >> 3;             // row-within-8 of staging
    const int cs = (lane & 7) ^ r8;       // inverse-swizzled source chunk
    const u16* ag = Ag + (size_t)(w * 64 + r8) * 2048 + cs * 8;
    const u16* bg = Bg + (size_t)(w * 64 + r8) * 2048 + cs * 8;
    const int fr = lane & 15;
    const int hq = lane >> 4;

    for (int kb = 0; kb < 2048; kb += 64) {
        #pragma unroll
        for (int ii = 0; ii < 8; ++ii)
            g2l16(ag + (size_t)(ii * 8) * 2048 + kb, &Al[w * 64 + ii * 8][0]);
        #pragma unroll
        for (int ii = 0; ii < 8; ++ii)
            g2l16(bg + (size_t)(ii * 8) * 2048 + kb, &Bl[w * 64 + ii * 8][0]);
        __syncthreads();

        #pragma unroll
        for (int kk = 0; kk < 2; ++kk) {
            bf16x8 af[8], bfn[4];
            #pragma unroll
            for (int m = 0; m < 8; ++m) {
                int row = m * 16 + fr;
                int pc = (kk * 4 + hq) ^ (row & 7);
                af[m] = ld_bf8(&Al[row][pc * 8]);
            }
            #pragma unroll
            for (int n = 0; n < 4; ++n) {
                int row = w * 64 + n * 16 + fr;
                int pc = (kk * 4 + hq) ^ (row & 7);
                bfn[n] = ld_bf8(&Bl[row][pc * 8]);
            }
            #pragma unroll
            for (int m = 0; m < 8; ++m)
                #pragma unroll
                for (int n = 0; n < 4; ++n)
                    acc.a[m][n] = __builtin_amdgcn_mfma_f32_16x16x32_bf16(af[m], bfn[n], acc.a[m][n], 0, 0, 0);
        }
        __syncthreads();
    }
}

// ---------------- QKV GEMM + fused RoPE epilogue ----------------
__global__ __launch_bounds__(128, 2)
void qkv_gemm(const u16* __restrict__ xb, const u16* __restrict__ Wt,
              const float2* __restrict__ tab,
              u16* __restrict__ Qb, u16* __restrict__ Kb, u16* __restrict__ Vb)
{
    __shared__ __align__(16) u16 Al[128][64];
    __shared__ __align__(16) u16 Bl[128][64];
    const int tid = threadIdx.x;
    const int lane = tid & 63;
    const int w = tid >> 6;
    const int m0  = blockIdx.x * 128;
    const int n0g = blockIdx.y * 128;

    GemmAcc acc = {};
    gemm_core_128(xb + (size_t)m0 * 2048, Wt + (size_t)n0g * 2048, Al, Bl, lane, w, acc);

    const int hq = lane >> 4;
    const int c0 = lane & 15;
    const int colbase = n0g + w * 64;
    const bool isV = (n0g >= 2560);
    const bool isQ = (n0g < 2048);

    #pragma unroll
    for (int m = 0; m < 8; ++m) {
        #pragma unroll
        for (int r = 0; r < 4; ++r) {
            int rw = m0 + m * 16 + hq * 4 + r;
            int b = rw >> 11, t = rw & 2047;
            if (!isV) {
                #pragma unroll
                for (int np = 0; np < 2; ++np) {
                    int dp = np * 16 + c0;
                    float2 cs = tab[t * 32 + dp];
                    float x1 = acc.a[m][np][r];
                    float x2 = acc.a[m][np + 2][r];
                    float lo = x1 * cs.x - x2 * cs.y;
                    float hi = x2 * cs.x + x1 * cs.y;
                    if (isQ) {
                        int h = colbase >> 6;
                        size_t base = (((size_t)b * 32 + h) * 2048 + t) * 64 + dp;
                        Qb[base]      = f2bf(lo);
                        Qb[base + 32] = f2bf(hi);
                    } else {
                        int hk = (colbase - 2048) >> 6;
                        size_t base = (((size_t)b * 8 + hk) * 2048 + t) * 64 + dp;
                        Kb[base]      = f2bf(lo);
                        Kb[base + 32] = f2bf(hi);
                    }
                }
            } else {
                #pragma unroll
                for (int n = 0; n < 4; ++n) {
                    int c2 = colbase + n * 16 + c0 - 2560;
                    int hk = c2 >> 6, d = c2 & 63;
                    Vb[(((size_t)b * 8 + hk) * 2048 + t) * 64 + d] = f2bf(acc.a[m][n][r]);
                }
            }
        }
    }
}

// ---------------- Output projection ----------------
__global__ __launch_bounds__(128, 2)
void out_gemm(const u16* __restrict__ A, const u16* __restrict__ Wt, float* __restrict__ C)
{
    __shared__ __align__(16) u16 Al[128][64];
    __shared__ __align__(16) u16 Bl[128][64];
    const int tid = threadIdx.x;
    const int lane = tid & 63;
    const int w = tid >> 6;
    const int m0 = blockIdx.x * 128;
    const int n0 = blockIdx.y * 128;

    GemmAcc acc = {};
    gemm_core_128(A + (size_t)m0 * 2048, Wt + (size_t)n0 * 2048, Al, Bl, lane, w, acc);

    const int hq = lane >> 4;
    const int c0 = lane & 15;
    #pragma unroll
    for (int m = 0; m < 8; ++m) {
        #pragma unroll
        for (int n = 0; n < 4; ++n) {
            #pragma unroll
            for (int r = 0; r < 4; ++r) {
                int rw = m0 + m * 16 + hq * 4 + r;
                int col = n0 + w * 64 + n * 16 + c0;
                C[(size_t)rw * 2048 + col] = acc.a[m][n][r];
            }
        }
    }
}

// ---------------- V transpose: (b,hk,t,d) -> (b,hk,d,t) ----------------
__global__ __launch_bounds__(256)
void vtrans(const u16* __restrict__ Vb, u16* __restrict__ Vt)
{
    __shared__ __align__(16) u16 tile[64][68];
    const int tid = threadIdx.x;
    const int t0 = blockIdx.x * 64;
    const size_t base = (size_t)blockIdx.y * 2048 * 64;
    {
        int r = tid >> 2, c0 = (tid & 3) * 16;
        const u16* src = Vb + base + (size_t)(t0 + r) * 64 + c0;
        *(u16x8*)&tile[r][c0]     = *(const u16x8*)src;
        *(u16x8*)&tile[r][c0 + 8] = *(const u16x8*)(src + 8);
    }
    __syncthreads();
    {
        int d = tid >> 2, j0 = (tid & 3) * 16;
        u16x8 o0, o1;
        #pragma unroll
        for (int i = 0; i < 8; ++i) o0[i] = tile[j0 + i][d];
        #pragma unroll
        for (int i = 0; i < 8; ++i) o1[i] = tile[j0 + 8 + i][d];
        u16* dst = Vt + base + (size_t)d * 2048 + t0 + j0;
        *(u16x8*)dst       = o0;
        *(u16x8*)(dst + 8) = o1;
    }
}

// ---------------- Flash attention: 8 waves, QBLK=128, swapped QK^T ----------------
__global__ __launch_bounds__(512)
void attn_kernel(const u16* __restrict__ Qb, const u16* __restrict__ Kb,
                 const u16* __restrict__ Vt, u16* __restrict__ AO)
{
    __shared__ __align__(16) u16 Kl[64][64];    // XOR-swizzled 16B chunks
    __shared__ __align__(16) u16 Vl[64][64];    // Vl[d][j], swizzled
    __shared__ __align__(16) u16 Pl[8][16][64]; // per-wave [q][k], swizzled

    const int tid = threadIdx.x;
    const int lane = tid & 63;
    const int w = tid >> 6;                 // 0..7
    const int q = lane & 15;
    const int hq = lane >> 4;
    const int q0 = (15 - blockIdx.x) * 128; // descending-work launch order
    const int bh = blockIdx.y;
    const int b = bh >> 5, h = bh & 31;
    const int hk = h >> 2;
    const size_t qbase  = (size_t)bh * 2048 * 64;
    const size_t kvbase = ((size_t)b * 8 + hk) * 2048 * 64;

    // staging: one 16B chunk per thread per array (512 thr = 64 rows x 8 chunks)
    const int sj = tid >> 3;                // row 0..63
    const int sc = tid & 7;                 // logical chunk
    const int sw = (sc ^ (sj & 7)) << 3;    // swizzled phys offset (u16 units)
    const int ca0 = ((hq    ) ^ (q & 7)) << 3;
    const int ca1 = ((hq + 4) ^ (q & 7)) << 3;

    bf16x8 qf0, qf1;
    {
        const u16* qp = Qb + qbase + (size_t)(q0 + w * 16 + q) * 64 + hq * 8;
        qf0 = ld_bf8(qp);
        qf1 = ld_bf8(qp + 32);
    }

    float mrun = -1e20f, lrun = 0.f;
    f32x4 o[4] = {};

    int kbeg = q0 - (WINDOW - 1);
    if (kbeg < 0) kbeg = 0;
    kbeg &= ~63;
    const int kend = q0 + 128;

    const int wrow_min = q0 + w * 16;
    const int wrow_max = wrow_min + 15;
    const int iq = wrow_min + q;

    u16x8 kr, vr;
    {
        const u16* kg = Kb + kvbase + (size_t)(kbeg + sj) * 64 + sc * 8;
        kr = *(const u16x8*)kg;
        const u16* vg = Vt + kvbase + (size_t)sj * 2048 + kbeg + sc * 8;
        vr = *(const u16x8*)vg;
    }
    *(u16x8*)&Kl[sj][sw] = kr;
    *(u16x8*)&Vl[sj][sw] = vr;
    __syncthreads();

    for (int k0 = kbeg; k0 < kend; k0 += 64) {
        const bool has_next = (k0 + 64 < kend);
        if (has_next) {
            const u16* kg = Kb + kvbase + (size_t)(k0 + 64 + sj) * 64 + sc * 8;
            kr = *(const u16x8*)kg;
            const u16* vg = Vt + kvbase + (size_t)sj * 2048 + k0 + 64 + sc * 8;
            vr = *(const u16x8*)vg;
        }

        bool active = (k0 <= wrow_max) && (k0 + 63 >= wrow_min - (WINDOW - 1));
        if (active) {
            f32x4 s[4];
            #pragma unroll
            for (int nf = 0; nf < 4; ++nf) {
                bf16x8 kb0 = ld_bf8(&Kl[nf * 16 + q][ca0]);
                bf16x8 kb1 = ld_bf8(&Kl[nf * 16 + q][ca1]);
                f32x4 a = {};
                a = __builtin_amdgcn_mfma_f32_16x16x32_bf16(kb0, qf0, a, 0, 0, 0);
                a = __builtin_amdgcn_mfma_f32_16x16x32_bf16(kb1, qf1, a, 0, 0, 0);
                s[nf] = a;
            }
            bool need_causal = (k0 + 63 > wrow_min);
            bool need_window = (wrow_max - k0) >= WINDOW;
            if (need_causal || need_window) {
                #pragma unroll
                for (int nf = 0; nf < 4; ++nf) {
                    #pragma unroll
                    for (int r = 0; r < 4; ++r) {
                        int j = k0 + nf * 16 + hq * 4 + r;
                        bool ok = (j <= iq) && (iq - j < WINDOW);
                        if (!ok) s[nf][r] = -1e30f;
                    }
                }
            }
            float tmax = s[0][0];
            #pragma unroll
            for (int nf = 0; nf < 4; ++nf)
                #pragma unroll
                for (int r = 0; r < 4; ++r) tmax = fmaxf(tmax, s[nf][r]);
            tmax = fmaxf(tmax, __shfl_xor(tmax, 16));
            tmax = fmaxf(tmax, __shfl_xor(tmax, 32));

            bool skip = __all(tmax <= mrun + 11.5f);
            float mnew = skip ? mrun : fmaxf(mrun, tmax);

            float tsum = 0.f;
            #pragma unroll
            for (int nf = 0; nf < 4; ++nf) {
                float p0 = exp2f_raw(s[nf][0] - mnew);
                float p1 = exp2f_raw(s[nf][1] - mnew);
                float p2 = exp2f_raw(s[nf][2] - mnew);
                float p3 = exp2f_raw(s[nf][3] - mnew);
                tsum += (p0 + p1) + (p2 + p3);
                u32x2 pw = { cvt_pk_bf16(p0, p1), cvt_pk_bf16(p2, p3) };
                int cpw = (((2 * nf + (hq >> 1)) ^ (q & 7)) << 3) + ((hq & 1) << 2);
                *(u32x2*)&Pl[w][q][cpw] = pw;
            }
            tsum += __shfl_xor(tsum, 16);
            tsum += __shfl_xor(tsum, 32);

            if (skip) {
                lrun += tsum;
            } else {
                float sc2 = exp2f_raw(mrun - mnew);
                mrun = mnew;
                lrun = lrun * sc2 + tsum;
                float osc[4];
                #pragma unroll
                for (int r = 0; r < 4; ++r)
                    osc[r] = __shfl(sc2, (lane & 48) + hq * 4 + r);
                #pragma unroll
                for (int nf = 0; nf < 4; ++nf)
                    #pragma unroll
                    for (int r = 0; r < 4; ++r)
                        o[nf][r] *= osc[r];
            }

            bf16x8 pa0 = ld_bf8(&Pl[w][q][ca0]);
            bf16x8 pa1 = ld_bf8(&Pl[w][q][ca1]);
            #pragma unroll
            for (int nf = 0; nf < 4; ++nf) {
                bf16x8 vb0 = ld_bf8(&Vl[nf * 16 + q][ca0]);
                bf16x8 vb1 = ld_bf8(&Vl[nf * 16 + q][ca1]);
                o[nf] = __builtin_amdgcn_mfma_f32_16x16x32_bf16(pa0, vb0, o[nf], 0, 0, 0);
                o[nf] = __builtin_amdgcn_mfma_f32_16x16x32_bf16(pa1, vb1, o[nf], 0, 0, 0);
            }
        }
        __syncthreads();
        if (has_next) {
            *(u16x8*)&Kl[sj][sw] = kr;
            *(u16x8*)&Vl[sj][sw] = vr;
        }
        __syncthreads();
    }

    float linv_own = 1.f / lrun;
    float linv[4];
    #pragma unroll
    for (int r = 0; r < 4; ++r)
        linv[r] = __shfl(linv_own, (lane & 48) + hq * 4 + r);
    #pragma unroll
    for (int nf = 0; nf < 4; ++nf) {
        #pragma unroll
        for (int r = 0; r < 4; ++r) {
            int i = q0 + w * 16 + hq * 4 + r;
            int d = nf * 16 + q;
            AO[((size_t)b * 2048 + i) * 2048 + h * 64 + d] = f2bf(o[nf][r] * linv[r]);
        }
    }
}

extern "C" void kernel_launch(void* const* d_in, const int* in_sizes, int n_in,
                              void* d_out, int out_size, void* d_ws, size_t ws_size,
                              hipStream_t stream)
{
    const float* x  = (const float*)d_in[0];
    const float* Wq = (const float*)d_in[1];
    const float* Wk = (const float*)d_in[2];
    const float* Wv = (const float*)d_in[3];
    const float* Wo = (const float*)d_in[4];
    float* out = (float*)d_out;

    u16* Qb    = (u16*)d_ws;                              //  8,388,608
    u16* Kb    = Qb    + (size_t)8388608;                 //  2,097,152
    u16* Vb    = Kb    + (size_t)2097152;                 //  2,097,152
    u16* Vt    = Vb    + (size_t)2097152;                 //  2,097,152
    u16* AO    = Vt    + (size_t)2097152;                 //  8,388,608
    u16* xb    = AO    + (size_t)8388608;                 //  8,388,608
    u16* WqkvT = xb    + (size_t)8388608;                 //  6,291,456  [3072][2048]
    u16* WoT   = WqkvT + (size_t)6291456;                 //  4,194,304  [2048][2048]
    float2* tab = (float2*)(WoT + (size_t)4194304);       //  512KB

    rope_tab_kernel<<<256, 256, 0, stream>>>(tab);
    convert_x<<<4096, 256, 0, stream>>>(x, xb);
    trans_conv_all<<<dim3(32, 32, 4), 256, 0, stream>>>(Wq, Wk, Wv, Wo, WqkvT, WoT);

    qkv_gemm<<<dim3(32, 24), 128, 0, stream>>>(xb, WqkvT, tab, Qb, Kb, Vb);
    vtrans<<<dim3(32, 16), 256, 0, stream>>>(Vb, Vt);
    attn_kernel<<<dim3(16, 64), 512, 0, stream>>>(Qb, Kb, Vt, AO);
    out_gemm<<<dim3(32, 16), 128, 0, stream>>>(AO, WoT, out);
}

// Round 11
// 198.086 us; speedup vs baseline: 1.2594x; 1.0018x over previous
//
#include <hip/hip_runtime.h>

typedef unsigned short u16;
typedef __attribute__((ext_vector_type(8))) unsigned short u16x8;
typedef __attribute__((ext_vector_type(2))) unsigned int u32x2;
typedef __attribute__((ext_vector_type(8))) __bf16 bf16x8;
typedef __attribute__((ext_vector_type(4))) float f32x4;

#define T_SEQ 2048
#define WINDOW 1024
// 0.125 * log2(e)
#define QSCALE 0.18033688011112042f

static __device__ __forceinline__ u16 f2bf(float f) {
    unsigned int u = __float_as_uint(f);
    u += 0x7fffu + ((u >> 16) & 1u);
    return (u16)(u >> 16);
}
static __device__ __forceinline__ float bf2f(u16 h) {
    return __uint_as_float(((unsigned int)h) << 16);
}
static __device__ __forceinline__ bf16x8 ld_bf8(const u16* p) {
    return __builtin_bit_cast(bf16x8, *(const u16x8*)p);
}
static __device__ __forceinline__ unsigned int cvt_pk_bf16(float lo, float hi) {
    unsigned int r;
    asm("v_cvt_pk_bf16_f32 %0, %1, %2" : "=v"(r) : "v"(lo), "v"(hi));
    return r;
}
static __device__ __forceinline__ float exp2f_raw(float x) {
#if __has_builtin(__builtin_amdgcn_exp2f)
    return __builtin_amdgcn_exp2f(x);
#else
    return exp2f(x);
#endif
}
// async global -> LDS, 16B per lane (wave-uniform LDS base + lane*16)
static __device__ __forceinline__ void g2l16(const void* g, void* l) {
    __builtin_amdgcn_global_load_lds(
        (const __attribute__((address_space(1))) void*)g,
        (__attribute__((address_space(3))) void*)l, 16, 0, 0);
}

// ---------------- RoPE cos/sin table: float2[2048][32] ----------------
__global__ __launch_bounds__(256)
void rope_tab_kernel(float2* __restrict__ tab)
{
    int idx = blockIdx.x * 256 + threadIdx.x;   // 65536
    int t = idx >> 5, dp = idx & 31;
    float inv_freq = __expf(-dp * 0.28782313662425574f); // ln(10000)/32
    float ang = (float)t * inv_freq;
    float s, c;
    sincosf(ang, &s, &c);
    tab[idx] = make_float2(c, s);
}

// ---------------- x fp32 -> bf16 (same layout) ----------------
__global__ __launch_bounds__(256)
void convert_x(const float* __restrict__ src, u16* __restrict__ dst)
{
    int i8 = blockIdx.x * 256 + threadIdx.x;
    size_t base = (size_t)i8 * 8;
    float4 a = *(const float4*)(src + base);
    float4 b = *(const float4*)(src + base + 4);
    u16x8 o = { f2bf(a.x), f2bf(a.y), f2bf(a.z), f2bf(a.w),
                f2bf(b.x), f2bf(b.y), f2bf(b.z), f2bf(b.w) };
    *(u16x8*)(dst + base) = o;
}

// ---------------- all W fp32 [2048][N] -> bf16 transposed [N][2048], scaled ----------------
__global__ __launch_bounds__(256)
void trans_conv_all(const float* __restrict__ Wq, const float* __restrict__ Wk,
                    const float* __restrict__ Wv, const float* __restrict__ Wo,
                    u16* __restrict__ WqkvT, u16* __restrict__ WoT)
{
    __shared__ __align__(16) u16 tile[64][72];
    const int z = blockIdx.z;
    const float* src; int N; float scale; u16* dst;
    if (z == 0)      { src = Wq; N = 2048; scale = QSCALE; dst = WqkvT; }
    else if (z == 1) { src = Wk; N = 512;  scale = 1.f;    dst = WqkvT + (size_t)2048 * 2048; }
    else if (z == 2) { src = Wv; N = 512;  scale = 1.f;    dst = WqkvT + (size_t)2560 * 2048; }
    else             { src = Wo; N = 2048; scale = 1.f;    dst = WoT; }
    if ((int)blockIdx.y * 64 >= N) return;

    const int tid = threadIdx.x;
    const int k0 = blockIdx.x * 64;
    const int n0 = blockIdx.y * 64;
    {
        int r = tid >> 2, c0 = (tid & 3) * 16;
        const float* sp = src + (size_t)(k0 + r) * N + n0 + c0;
        float4 v0 = *(const float4*)(sp + 0);
        float4 v1 = *(const float4*)(sp + 4);
        float4 v2 = *(const float4*)(sp + 8);
        float4 v3 = *(const float4*)(sp + 12);
        u16x8 s0 = { f2bf(v0.x * scale), f2bf(v0.y * scale), f2bf(v0.z * scale), f2bf(v0.w * scale),
                     f2bf(v1.x * scale), f2bf(v1.y * scale), f2bf(v1.z * scale), f2bf(v1.w * scale) };
        u16x8 s1 = { f2bf(v2.x * scale), f2bf(v2.y * scale), f2bf(v2.z * scale), f2bf(v2.w * scale),
                     f2bf(v3.x * scale), f2bf(v3.y * scale), f2bf(v3.z * scale), f2bf(v3.w * scale) };
        *(u16x8*)&tile[r][c0]     = s0;
        *(u16x8*)&tile[r][c0 + 8] = s1;
    }
    __syncthreads();
    {
        int n = tid >> 2, j0 = (tid & 3) * 16;
        u16x8 o0, o1;
        #pragma unroll
        for (int i = 0; i < 8; ++i) o0[i] = tile[j0 + i][n];
        #pragma unroll
        for (int i = 0; i < 8; ++i) o1[i] = tile[j0 + 8 + i][n];
        u16* dp = dst + (size_t)(n0 + n) * 2048 + k0 + j0;
        *(u16x8*)dp       = o0;
        *(u16x8*)(dp + 8) = o1;
    }
}

// ================= GEMM core: 128 threads (2 waves), block 128x128 =================
struct GemmAcc { f32x4 a[8][4]; };

__device__ __forceinline__ void gemm_core_128(const u16* __restrict__ Ag,
                                              const u16* __restrict__ Bg,
                                              u16 (*Al)[64], u16 (*Bl)[64],
                                              int lane, int w, GemmAcc& acc)
{
    const int r8 = lane >> 3;             // row-within-8 of staging
    const int cs = (lane & 7) ^ r8;       // inverse-swizzled source chunk
    const u16* ag = Ag + (size_t)(w * 64 + r8) * 2048 + cs * 8;
    const u16* bg = Bg + (size_t)(w * 64 + r8) * 2048 + cs * 8;
    const int fr = lane & 15;
    const int hq = lane >> 4;

    for (int kb = 0; kb < 2048; kb += 64) {
        #pragma unroll
        for (int ii = 0; ii < 8; ++ii)
            g2l16(ag + (size_t)(ii * 8) * 2048 + kb, &Al[w * 64 + ii * 8][0]);
        #pragma unroll
        for (int ii = 0; ii < 8; ++ii)
            g2l16(bg + (size_t)(ii * 8) * 2048 + kb, &Bl[w * 64 + ii * 8][0]);
        __syncthreads();

        #pragma unroll
        for (int kk = 0; kk < 2; ++kk) {
            bf16x8 af[8], bfn[4];
            #pragma unroll
            for (int m = 0; m < 8; ++m) {
                int row = m * 16 + fr;
                int pc = (kk * 4 + hq) ^ (row & 7);
                af[m] = ld_bf8(&Al[row][pc * 8]);
            }
            #pragma unroll
            for (int n = 0; n < 4; ++n) {
                int row = w * 64 + n * 16 + fr;
                int pc = (kk * 4 + hq) ^ (row & 7);
                bfn[n] = ld_bf8(&Bl[row][pc * 8]);
            }
            #pragma unroll
            for (int m = 0; m < 8; ++m)
                #pragma unroll
                for (int n = 0; n < 4; ++n)
                    acc.a[m][n] = __builtin_amdgcn_mfma_f32_16x16x32_bf16(af[m], bfn[n], acc.a[m][n], 0, 0, 0);
        }
        __syncthreads();
    }
}

// ---------------- QKV GEMM + fused RoPE epilogue ----------------
__global__ __launch_bounds__(128, 2)
void qkv_gemm(const u16* __restrict__ xb, const u16* __restrict__ Wt,
              const float2* __restrict__ tab,
              u16* __restrict__ Qb, u16* __restrict__ Kb, u16* __restrict__ Vb)
{
    __shared__ __align__(16) u16 Al[128][64];
    __shared__ __align__(16) u16 Bl[128][64];
    const int tid = threadIdx.x;
    const int lane = tid & 63;
    const int w = tid >> 6;
    const int m0  = blockIdx.x * 128;
    const int n0g = blockIdx.y * 128;

    GemmAcc acc = {};
    gemm_core_128(xb + (size_t)m0 * 2048, Wt + (size_t)n0g * 2048, Al, Bl, lane, w, acc);

    const int hq = lane >> 4;
    const int c0 = lane & 15;
    const int colbase = n0g + w * 64;
    const bool isV = (n0g >= 2560);
    const bool isQ = (n0g < 2048);

    #pragma unroll
    for (int m = 0; m < 8; ++m) {
        #pragma unroll
        for (int r = 0; r < 4; ++r) {
            int rw = m0 + m * 16 + hq * 4 + r;
            int b = rw >> 11, t = rw & 2047;
            if (!isV) {
                #pragma unroll
                for (int np = 0; np < 2; ++np) {
                    int dp = np * 16 + c0;
                    float2 cs = tab[t * 32 + dp];
                    float x1 = acc.a[m][np][r];
                    float x2 = acc.a[m][np + 2][r];
                    float lo = x1 * cs.x - x2 * cs.y;
                    float hi = x2 * cs.x + x1 * cs.y;
                    if (isQ) {
                        int h = colbase >> 6;
                        size_t base = (((size_t)b * 32 + h) * 2048 + t) * 64 + dp;
                        Qb[base]      = f2bf(lo);
                        Qb[base + 32] = f2bf(hi);
                    } else {
                        int hk = (colbase - 2048) >> 6;
                        size_t base = (((size_t)b * 8 + hk) * 2048 + t) * 64 + dp;
                        Kb[base]      = f2bf(lo);
                        Kb[base + 32] = f2bf(hi);
                    }
                }
            } else {
                #pragma unroll
                for (int n = 0; n < 4; ++n) {
                    int c2 = colbase + n * 16 + c0 - 2560;
                    int hk = c2 >> 6, d = c2 & 63;
                    Vb[(((size_t)b * 8 + hk) * 2048 + t) * 64 + d] = f2bf(acc.a[m][n][r]);
                }
            }
        }
    }
}

// ---------------- Output projection ----------------
__global__ __launch_bounds__(128, 2)
void out_gemm(const u16* __restrict__ A, const u16* __restrict__ Wt, float* __restrict__ C)
{
    __shared__ __align__(16) u16 Al[128][64];
    __shared__ __align__(16) u16 Bl[128][64];
    const int tid = threadIdx.x;
    const int lane = tid & 63;
    const int w = tid >> 6;
    const int m0 = blockIdx.x * 128;
    const int n0 = blockIdx.y * 128;

    GemmAcc acc = {};
    gemm_core_128(A + (size_t)m0 * 2048, Wt + (size_t)n0 * 2048, Al, Bl, lane, w, acc);

    const int hq = lane >> 4;
    const int c0 = lane & 15;
    #pragma unroll
    for (int m = 0; m < 8; ++m) {
        #pragma unroll
        for (int n = 0; n < 4; ++n) {
            #pragma unroll
            for (int r = 0; r < 4; ++r) {
                int rw = m0 + m * 16 + hq * 4 + r;
                int col = n0 + w * 64 + n * 16 + c0;
                C[(size_t)rw * 2048 + col] = acc.a[m][n][r];
            }
        }
    }
}

// ---------------- V transpose: (b,hk,t,d) -> (b,hk,d,t) ----------------
__global__ __launch_bounds__(256)
void vtrans(const u16* __restrict__ Vb, u16* __restrict__ Vt)
{
    __shared__ __align__(16) u16 tile[64][68];
    const int tid = threadIdx.x;
    const int t0 = blockIdx.x * 64;
    const size_t base = (size_t)blockIdx.y * 2048 * 64;
    {
        int r = tid >> 2, c0 = (tid & 3) * 16;
        const u16* src = Vb + base + (size_t)(t0 + r) * 64 + c0;
        *(u16x8*)&tile[r][c0]     = *(const u16x8*)src;
        *(u16x8*)&tile[r][c0 + 8] = *(const u16x8*)(src + 8);
    }
    __syncthreads();
    {
        int d = tid >> 2, j0 = (tid & 3) * 16;
        u16x8 o0, o1;
        #pragma unroll
        for (int i = 0; i < 8; ++i) o0[i] = tile[j0 + i][d];
        #pragma unroll
        for (int i = 0; i < 8; ++i) o1[i] = tile[j0 + 8 + i][d];
        u16* dst = Vt + base + (size_t)d * 2048 + t0 + j0;
        *(u16x8*)dst       = o0;
        *(u16x8*)(dst + 8) = o1;
    }
}

// ---------------- Flash attention: 8 waves, QBLK=128, swapped QK^T ----------------
__global__ __launch_bounds__(512)
void attn_kernel(const u16* __restrict__ Qb, const u16* __restrict__ Kb,
                 const u16* __restrict__ Vt, u16* __restrict__ AO)
{
    __shared__ __align__(16) u16 Kl[64][64];    // XOR-swizzled 16B chunks
    __shared__ __align__(16) u16 Vl[64][64];    // Vl[d][j], swizzled
    __shared__ __align__(16) u16 Pl[8][16][64]; // per-wave [q][k], swizzled

    const int tid = threadIdx.x;
    const int lane = tid & 63;
    const int w = tid >> 6;                 // 0..7
    const int q = lane & 15;
    const int hq = lane >> 4;
    const int q0 = (15 - blockIdx.x) * 128; // descending-work launch order
    const int bh = blockIdx.y;
    const int b = bh >> 5, h = bh & 31;
    const int hk = h >> 2;
    const size_t qbase  = (size_t)bh * 2048 * 64;
    const size_t kvbase = ((size_t)b * 8 + hk) * 2048 * 64;

    // staging: one 16B chunk per thread per array (512 thr = 64 rows x 8 chunks)
    const int sj = tid >> 3;                // row 0..63
    const int sc = tid & 7;                 // logical chunk
    const int sw = (sc ^ (sj & 7)) << 3;    // swizzled phys offset (u16 units)
    const int ca0 = ((hq    ) ^ (q & 7)) << 3;
    const int ca1 = ((hq + 4) ^ (q & 7)) << 3;

    bf16x8 qf0, qf1;
    {
        const u16* qp = Qb + qbase + (size_t)(q0 + w * 16 + q) * 64 + hq * 8;
        qf0 = ld_bf8(qp);
        qf1 = ld_bf8(qp + 32);
    }

    float mrun = -1e20f, lrun = 0.f;
    f32x4 o[4] = {};

    int kbeg = q0 - (WINDOW - 1);
    if (kbeg < 0) kbeg = 0;
    kbeg &= ~63;
    const int kend = q0 + 128;

    const int wrow_min = q0 + w * 16;
    const int wrow_max = wrow_min + 15;
    const int iq = wrow_min + q;

    u16x8 kr, vr;
    {
        const u16* kg = Kb + kvbase + (size_t)(kbeg + sj) * 64 + sc * 8;
        kr = *(const u16x8*)kg;
        const u16* vg = Vt + kvbase + (size_t)sj * 2048 + kbeg + sc * 8;
        vr = *(const u16x8*)vg;
    }
    *(u16x8*)&Kl[sj][sw] = kr;
    *(u16x8*)&Vl[sj][sw] = vr;
    __syncthreads();

    for (int k0 = kbeg; k0 < kend; k0 += 64) {
        const bool has_next = (k0 + 64 < kend);
        if (has_next) {
            const u16* kg = Kb + kvbase + (size_t)(k0 + 64 + sj) * 64 + sc * 8;
            kr = *(const u16x8*)kg;
            const u16* vg = Vt + kvbase + (size_t)sj * 2048 + k0 + 64 + sc * 8;
            vr = *(const u16x8*)vg;
        }

        bool active = (k0 <= wrow_max) && (k0 + 63 >= wrow_min - (WINDOW - 1));
        if (active) {
            f32x4 s[4];
            #pragma unroll
            for (int nf = 0; nf < 4; ++nf) {
                bf16x8 kb0 = ld_bf8(&Kl[nf * 16 + q][ca0]);
                bf16x8 kb1 = ld_bf8(&Kl[nf * 16 + q][ca1]);
                f32x4 a = {};
                a = __builtin_amdgcn_mfma_f32_16x16x32_bf16(kb0, qf0, a, 0, 0, 0);
                a = __builtin_amdgcn_mfma_f32_16x16x32_bf16(kb1, qf1, a, 0, 0, 0);
                s[nf] = a;
            }
            bool need_causal = (k0 + 63 > wrow_min);
            bool need_window = (wrow_max - k0) >= WINDOW;
            if (need_causal || need_window) {
                #pragma unroll
                for (int nf = 0; nf < 4; ++nf) {
                    #pragma unroll
                    for (int r = 0; r < 4; ++r) {
                        int j = k0 + nf * 16 + hq * 4 + r;
                        bool ok = (j <= iq) && (iq - j < WINDOW);
                        if (!ok) s[nf][r] = -1e30f;
                    }
                }
            }
            float tmax = s[0][0];
            #pragma unroll
            for (int nf = 0; nf < 4; ++nf)
                #pragma unroll
                for (int r = 0; r < 4; ++r) tmax = fmaxf(tmax, s[nf][r]);
            tmax = fmaxf(tmax, __shfl_xor(tmax, 16));
            tmax = fmaxf(tmax, __shfl_xor(tmax, 32));

            bool skip = __all(tmax <= mrun + 11.5f);
            float mnew = skip ? mrun : fmaxf(mrun, tmax);

            float tsum = 0.f;
            #pragma unroll
            for (int nf = 0; nf < 4; ++nf) {
                float p0 = exp2f_raw(s[nf][0] - mnew);
                float p1 = exp2f_raw(s[nf][1] - mnew);
                float p2 = exp2f_raw(s[nf][2] - mnew);
                float p3 = exp2f_raw(s[nf][3] - mnew);
                tsum += (p0 + p1) + (p2 + p3);
                u32x2 pw = { cvt_pk_bf16(p0, p1), cvt_pk_bf16(p2, p3) };
                int cpw = (((2 * nf + (hq >> 1)) ^ (q & 7)) << 3) + ((hq & 1) << 2);
                *(u32x2*)&Pl[w][q][cpw] = pw;
            }
            tsum += __shfl_xor(tsum, 16);
            tsum += __shfl_xor(tsum, 32);

            if (skip) {
                lrun += tsum;
            } else {
                float sc2 = exp2f_raw(mrun - mnew);
                mrun = mnew;
                lrun = lrun * sc2 + tsum;
                float osc[4];
                #pragma unroll
                for (int r = 0; r < 4; ++r)
                    osc[r] = __shfl(sc2, (lane & 48) + hq * 4 + r);
                #pragma unroll
                for (int nf = 0; nf < 4; ++nf)
                    #pragma unroll
                    for (int r = 0; r < 4; ++r)
                        o[nf][r] *= osc[r];
            }

            bf16x8 pa0 = ld_bf8(&Pl[w][q][ca0]);
            bf16x8 pa1 = ld_bf8(&Pl[w][q][ca1]);
            #pragma unroll
            for (int nf = 0; nf < 4; ++nf) {
                bf16x8 vb0 = ld_bf8(&Vl[nf * 16 + q][ca0]);
                bf16x8 vb1 = ld_bf8(&Vl[nf * 16 + q][ca1]);
                o[nf] = __builtin_amdgcn_mfma_f32_16x16x32_bf16(pa0, vb0, o[nf], 0, 0, 0);
                o[nf] = __builtin_amdgcn_mfma_f32_16x16x32_bf16(pa1, vb1, o[nf], 0, 0, 0);
            }
        }
        __syncthreads();
        if (has_next) {
            *(u16x8*)&Kl[sj][sw] = kr;
            *(u16x8*)&Vl[sj][sw] = vr;
        }
        __syncthreads();
    }

    float linv_own = 1.f / lrun;
    float linv[4];
    #pragma unroll
    for (int r = 0; r < 4; ++r)
        linv[r] = __shfl(linv_own, (lane & 48) + hq * 4 + r);
    #pragma unroll
    for (int nf = 0; nf < 4; ++nf) {
        #pragma unroll
        for (int r = 0; r < 4; ++r) {
            int i = q0 + w * 16 + hq * 4 + r;
            int d = nf * 16 + q;
            AO[((size_t)b * 2048 + i) * 2048 + h * 64 + d] = f2bf(o[nf][r] * linv[r]);
        }
    }
}

extern "C" void kernel_launch(void* const* d_in, const int* in_sizes, int n_in,
                              void* d_out, int out_size, void* d_ws, size_t ws_size,
                              hipStream_t stream)
{
    const float* x  = (const float*)d_in[0];
    const float* Wq = (const float*)d_in[1];
    const float* Wk = (const float*)d_in[2];
    const float* Wv = (const float*)d_in[3];
    const float* Wo = (const float*)d_in[4];
    float* out = (float*)d_out;

    u16* Qb    = (u16*)d_ws;                              //  8,388,608
    u16* Kb    = Qb    + (size_t)8388608;                 //  2,097,152
    u16* Vb    = Kb    + (size_t)2097152;                 //  2,097,152
    u16* Vt    = Vb    + (size_t)2097152;                 //  2,097,152
    u16* AO    = Vt    + (size_t)2097152;                 //  8,388,608
    u16* xb    = AO    + (size_t)8388608;                 //  8,388,608
    u16* WqkvT = xb    + (size_t)8388608;                 //  6,291,456  [3072][2048]
    u16* WoT   = WqkvT + (size_t)6291456;                 //  4,194,304  [2048][2048]
    float2* tab = (float2*)(WoT + (size_t)4194304);       //  512KB

    rope_tab_kernel<<<256, 256, 0, stream>>>(tab);
    convert_x<<<4096, 256, 0, stream>>>(x, xb);
    trans_conv_all<<<dim3(32, 32, 4), 256, 0, stream>>>(Wq, Wk, Wv, Wo, WqkvT, WoT);

    qkv_gemm<<<dim3(32, 24), 128, 0, stream>>>(xb, WqkvT, tab, Qb, Kb, Vb);
    vtrans<<<dim3(32, 16), 256, 0, stream>>>(Vb, Vt);
    attn_kernel<<<dim3(16, 64), 512, 0, stream>>>(Qb, Kb, Vt, AO);
    out_gemm<<<dim3(32, 16), 128, 0, stream>>>(AO, WoT, out);
}

// Round 12
// 188.399 us; speedup vs baseline: 1.3242x; 1.0514x over previous
//
#include <hip/hip_runtime.h>

typedef unsigned short u16;
typedef __attribute__((ext_vector_type(8))) unsigned short u16x8;
typedef __attribute__((ext_vector_type(2))) unsigned int u32x2;
typedef __attribute__((ext_vector_type(8))) __bf16 bf16x8;
typedef __attribute__((ext_vector_type(4))) float f32x4;

#define T_SEQ 2048
#define WINDOW 1024
// 0.125 * log2(e)
#define QSCALE 0.18033688011112042f

static __device__ __forceinline__ u16 f2bf(float f) {
    unsigned int u = __float_as_uint(f);
    u += 0x7fffu + ((u >> 16) & 1u);
    return (u16)(u >> 16);
}
static __device__ __forceinline__ float bf2f(u16 h) {
    return __uint_as_float(((unsigned int)h) << 16);
}
static __device__ __forceinline__ bf16x8 ld_bf8(const u16* p) {
    return __builtin_bit_cast(bf16x8, *(const u16x8*)p);
}
static __device__ __forceinline__ unsigned int cvt_pk_bf16(float lo, float hi) {
    unsigned int r;
    asm("v_cvt_pk_bf16_f32 %0, %1, %2" : "=v"(r) : "v"(lo), "v"(hi));
    return r;
}
static __device__ __forceinline__ float exp2f_raw(float x) {
#if __has_builtin(__builtin_amdgcn_exp2f)
    return __builtin_amdgcn_exp2f(x);
#else
    return exp2f(x);
#endif
}
// async global -> LDS, 16B per lane (wave-uniform LDS base + lane*16)
static __device__ __forceinline__ void g2l16(const void* g, void* l) {
    __builtin_amdgcn_global_load_lds(
        (const __attribute__((address_space(1))) void*)g,
        (__attribute__((address_space(3))) void*)l, 16, 0, 0);
}

// per-CU work-balance permutation for attn q-tiles: quartets {a,a+4,a+8,a+12}
// map to tile-counts summing to exactly 54 each (see round-11 analysis)
__device__ const int q_tmap[16] = {0, 1, 2, 3, 7, 6, 5, 4, 8, 10, 12, 14, 9, 11, 13, 15};

// ---------------- RoPE cos/sin table: float2[2048][32] ----------------
__global__ __launch_bounds__(256)
void rope_tab_kernel(float2* __restrict__ tab)
{
    int idx = blockIdx.x * 256 + threadIdx.x;   // 65536
    int t = idx >> 5, dp = idx & 31;
    float inv_freq = __expf(-dp * 0.28782313662425574f); // ln(10000)/32
    float ang = (float)t * inv_freq;
    float s, c;
    sincosf(ang, &s, &c);
    tab[idx] = make_float2(c, s);
}

// ---------------- x fp32 -> bf16 (same layout) ----------------
__global__ __launch_bounds__(256)
void convert_x(const float* __restrict__ src, u16* __restrict__ dst)
{
    int i8 = blockIdx.x * 256 + threadIdx.x;
    size_t base = (size_t)i8 * 8;
    float4 a = *(const float4*)(src + base);
    float4 b = *(const float4*)(src + base + 4);
    u16x8 o = { f2bf(a.x), f2bf(a.y), f2bf(a.z), f2bf(a.w),
                f2bf(b.x), f2bf(b.y), f2bf(b.z), f2bf(b.w) };
    *(u16x8*)(dst + base) = o;
}

// ---------------- all W fp32 [2048][N] -> bf16 transposed [N][2048], scaled ----------------
__global__ __launch_bounds__(256)
void trans_conv_all(const float* __restrict__ Wq, const float* __restrict__ Wk,
                    const float* __restrict__ Wv, const float* __restrict__ Wo,
                    u16* __restrict__ WqkvT, u16* __restrict__ WoT)
{
    __shared__ __align__(16) u16 tile[64][72];
    const int z = blockIdx.z;
    const float* src; int N; float scale; u16* dst;
    if (z == 0)      { src = Wq; N = 2048; scale = QSCALE; dst = WqkvT; }
    else if (z == 1) { src = Wk; N = 512;  scale = 1.f;    dst = WqkvT + (size_t)2048 * 2048; }
    else if (z == 2) { src = Wv; N = 512;  scale = 1.f;    dst = WqkvT + (size_t)2560 * 2048; }
    else             { src = Wo; N = 2048; scale = 1.f;    dst = WoT; }
    if ((int)blockIdx.y * 64 >= N) return;

    const int tid = threadIdx.x;
    const int k0 = blockIdx.x * 64;
    const int n0 = blockIdx.y * 64;
    {
        int r = tid >> 2, c0 = (tid & 3) * 16;
        const float* sp = src + (size_t)(k0 + r) * N + n0 + c0;
        float4 v0 = *(const float4*)(sp + 0);
        float4 v1 = *(const float4*)(sp + 4);
        float4 v2 = *(const float4*)(sp + 8);
        float4 v3 = *(const float4*)(sp + 12);
        u16x8 s0 = { f2bf(v0.x * scale), f2bf(v0.y * scale), f2bf(v0.z * scale), f2bf(v0.w * scale),
                     f2bf(v1.x * scale), f2bf(v1.y * scale), f2bf(v1.z * scale), f2bf(v1.w * scale) };
        u16x8 s1 = { f2bf(v2.x * scale), f2bf(v2.y * scale), f2bf(v2.z * scale), f2bf(v2.w * scale),
                     f2bf(v3.x * scale), f2bf(v3.y * scale), f2bf(v3.z * scale), f2bf(v3.w * scale) };
        *(u16x8*)&tile[r][c0]     = s0;
        *(u16x8*)&tile[r][c0 + 8] = s1;
    }
    __syncthreads();
    {
        int n = tid >> 2, j0 = (tid & 3) * 16;
        u16x8 o0, o1;
        #pragma unroll
        for (int i = 0; i < 8; ++i) o0[i] = tile[j0 + i][n];
        #pragma unroll
        for (int i = 0; i < 8; ++i) o1[i] = tile[j0 + 8 + i][n];
        u16* dp = dst + (size_t)(n0 + n) * 2048 + k0 + j0;
        *(u16x8*)dp       = o0;
        *(u16x8*)(dp + 8) = o1;
    }
}

// ================= GEMM core: 128 threads (2 waves), block 128x128 =================
struct GemmAcc { f32x4 a[8][4]; };

__device__ __forceinline__ void gemm_core_128(const u16* __restrict__ Ag,
                                              const u16* __restrict__ Bg,
                                              u16 (*Al)[64], u16 (*Bl)[64],
                                              int lane, int w, GemmAcc& acc)
{
    const int r8 = lane >> 3;             // row-within-8 of staging
    const int cs = (lane & 7) ^ r8;       // inverse-swizzled source chunk
    const u16* ag = Ag + (size_t)(w * 64 + r8) * 2048 + cs * 8;
    const u16* bg = Bg + (size_t)(w * 64 + r8) * 2048 + cs * 8;
    const int fr = lane & 15;
    const int hq = lane >> 4;

    for (int kb = 0; kb < 2048; kb += 64) {
        #pragma unroll
        for (int ii = 0; ii < 8; ++ii)
            g2l16(ag + (size_t)(ii * 8) * 2048 + kb, &Al[w * 64 + ii * 8][0]);
        #pragma unroll
        for (int ii = 0; ii < 8; ++ii)
            g2l16(bg + (size_t)(ii * 8) * 2048 + kb, &Bl[w * 64 + ii * 8][0]);
        __syncthreads();

        #pragma unroll
        for (int kk = 0; kk < 2; ++kk) {
            bf16x8 af[8], bfn[4];
            #pragma unroll
            for (int m = 0; m < 8; ++m) {
                int row = m * 16 + fr;
                int pc = (kk * 4 + hq) ^ (row & 7);
                af[m] = ld_bf8(&Al[row][pc * 8]);
            }
            #pragma unroll
            for (int n = 0; n < 4; ++n) {
                int row = w * 64 + n * 16 + fr;
                int pc = (kk * 4 + hq) ^ (row & 7);
                bfn[n] = ld_bf8(&Bl[row][pc * 8]);
            }
            #pragma unroll
            for (int m = 0; m < 8; ++m)
                #pragma unroll
                for (int n = 0; n < 4; ++n)
                    acc.a[m][n] = __builtin_amdgcn_mfma_f32_16x16x32_bf16(af[m], bfn[n], acc.a[m][n], 0, 0, 0);
        }
        __syncthreads();
    }
}

// ---------------- QKV GEMM + fused RoPE epilogue ----------------
__global__ __launch_bounds__(128, 2)
void qkv_gemm(const u16* __restrict__ xb, const u16* __restrict__ Wt,
              const float2* __restrict__ tab,
              u16* __restrict__ Qb, u16* __restrict__ Kb, u16* __restrict__ Vb)
{
    __shared__ __align__(16) u16 Al[128][64];
    __shared__ __align__(16) u16 Bl[128][64];
    const int tid = threadIdx.x;
    const int lane = tid & 63;
    const int w = tid >> 6;
    const int m0  = blockIdx.x * 128;
    const int n0g = blockIdx.y * 128;

    GemmAcc acc = {};
    gemm_core_128(xb + (size_t)m0 * 2048, Wt + (size_t)n0g * 2048, Al, Bl, lane, w, acc);

    const int hq = lane >> 4;
    const int c0 = lane & 15;
    const int colbase = n0g + w * 64;
    const bool isV = (n0g >= 2560);
    const bool isQ = (n0g < 2048);

    #pragma unroll
    for (int m = 0; m < 8; ++m) {
        #pragma unroll
        for (int r = 0; r < 4; ++r) {
            int rw = m0 + m * 16 + hq * 4 + r;
            int b = rw >> 11, t = rw & 2047;
            if (!isV) {
                #pragma unroll
                for (int np = 0; np < 2; ++np) {
                    int dp = np * 16 + c0;
                    float2 cs = tab[t * 32 + dp];
                    float x1 = acc.a[m][np][r];
                    float x2 = acc.a[m][np + 2][r];
                    float lo = x1 * cs.x - x2 * cs.y;
                    float hi = x2 * cs.x + x1 * cs.y;
                    if (isQ) {
                        int h = colbase >> 6;
                        size_t base = (((size_t)b * 32 + h) * 2048 + t) * 64 + dp;
                        Qb[base]      = f2bf(lo);
                        Qb[base + 32] = f2bf(hi);
                    } else {
                        int hk = (colbase - 2048) >> 6;
                        size_t base = (((size_t)b * 8 + hk) * 2048 + t) * 64 + dp;
                        Kb[base]      = f2bf(lo);
                        Kb[base + 32] = f2bf(hi);
                    }
                }
            } else {
                #pragma unroll
                for (int n = 0; n < 4; ++n) {
                    int c2 = colbase + n * 16 + c0 - 2560;
                    int hk = c2 >> 6, d = c2 & 63;
                    Vb[(((size_t)b * 8 + hk) * 2048 + t) * 64 + d] = f2bf(acc.a[m][n][r]);
                }
            }
        }
    }
}

// ---------------- Output projection ----------------
__global__ __launch_bounds__(128, 2)
void out_gemm(const u16* __restrict__ A, const u16* __restrict__ Wt, float* __restrict__ C)
{
    __shared__ __align__(16) u16 Al[128][64];
    __shared__ __align__(16) u16 Bl[128][64];
    const int tid = threadIdx.x;
    const int lane = tid & 63;
    const int w = tid >> 6;
    const int m0 = blockIdx.x * 128;
    const int n0 = blockIdx.y * 128;

    GemmAcc acc = {};
    gemm_core_128(A + (size_t)m0 * 2048, Wt + (size_t)n0 * 2048, Al, Bl, lane, w, acc);

    const int hq = lane >> 4;
    const int c0 = lane & 15;
    #pragma unroll
    for (int m = 0; m < 8; ++m) {
        #pragma unroll
        for (int n = 0; n < 4; ++n) {
            #pragma unroll
            for (int r = 0; r < 4; ++r) {
                int rw = m0 + m * 16 + hq * 4 + r;
                int col = n0 + w * 64 + n * 16 + c0;
                C[(size_t)rw * 2048 + col] = acc.a[m][n][r];
            }
        }
    }
}

// ---------------- V transpose: (b,hk,t,d) -> (b,hk,d,t) ----------------
__global__ __launch_bounds__(256)
void vtrans(const u16* __restrict__ Vb, u16* __restrict__ Vt)
{
    __shared__ __align__(16) u16 tile[64][68];
    const int tid = threadIdx.x;
    const int t0 = blockIdx.x * 64;
    const size_t base = (size_t)blockIdx.y * 2048 * 64;
    {
        int r = tid >> 2, c0 = (tid & 3) * 16;
        const u16* src = Vb + base + (size_t)(t0 + r) * 64 + c0;
        *(u16x8*)&tile[r][c0]     = *(const u16x8*)src;
        *(u16x8*)&tile[r][c0 + 8] = *(const u16x8*)(src + 8);
    }
    __syncthreads();
    {
        int d = tid >> 2, j0 = (tid & 3) * 16;
        u16x8 o0, o1;
        #pragma unroll
        for (int i = 0; i < 8; ++i) o0[i] = tile[j0 + i][d];
        #pragma unroll
        for (int i = 0; i < 8; ++i) o1[i] = tile[j0 + 8 + i][d];
        u16* dst = Vt + base + (size_t)d * 2048 + t0 + j0;
        *(u16x8*)dst       = o0;
        *(u16x8*)(dst + 8) = o1;
    }
}

// ---------------- Flash attention: 8 waves, QBLK=128, CU-work-balanced grid ----------------
__global__ __launch_bounds__(512)
void attn_kernel(const u16* __restrict__ Qb, const u16* __restrict__ Kb,
                 const u16* __restrict__ Vt, u16* __restrict__ AO)
{
    __shared__ __align__(16) u16 Kl[64][64];    // XOR-swizzled 16B chunks
    __shared__ __align__(16) u16 Vl[64][64];    // Vl[d][j], swizzled
    __shared__ __align__(16) u16 Pl[8][16][64]; // per-wave [q][k], swizzled

    const int tid = threadIdx.x;
    const int lane = tid & 63;
    const int w = tid >> 6;                 // 0..7
    const int q = lane & 15;
    const int hq = lane >> 4;
    const int q0 = q_tmap[blockIdx.y] * 128;   // balanced q-tile per CU quartet
    const int bh = blockIdx.x;                 // bh fast -> CU quartets span q-tiles
    const int b = bh >> 5, h = bh & 31;
    const int hk = h >> 2;
    const size_t qbase  = (size_t)bh * 2048 * 64;
    const size_t kvbase = ((size_t)b * 8 + hk) * 2048 * 64;

    // staging: one 16B chunk per thread per array (512 thr = 64 rows x 8 chunks)
    const int sj = tid >> 3;                // row 0..63
    const int sc = tid & 7;                 // logical chunk
    const int sw = (sc ^ (sj & 7)) << 3;    // swizzled phys offset (u16 units)
    const int ca0 = ((hq    ) ^ (q & 7)) << 3;
    const int ca1 = ((hq + 4) ^ (q & 7)) << 3;

    bf16x8 qf0, qf1;
    {
        const u16* qp = Qb + qbase + (size_t)(q0 + w * 16 + q) * 64 + hq * 8;
        qf0 = ld_bf8(qp);
        qf1 = ld_bf8(qp + 32);
    }

    float mrun = -1e20f, lrun = 0.f;
    f32x4 o[4] = {};

    int kbeg = q0 - (WINDOW - 1);
    if (kbeg < 0) kbeg = 0;
    kbeg &= ~63;
    const int kend = q0 + 128;

    const int wrow_min = q0 + w * 16;
    const int wrow_max = wrow_min + 15;
    const int iq = wrow_min + q;

    u16x8 kr, vr;
    {
        const u16* kg = Kb + kvbase + (size_t)(kbeg + sj) * 64 + sc * 8;
        kr = *(const u16x8*)kg;
        const u16* vg = Vt + kvbase + (size_t)sj * 2048 + kbeg + sc * 8;
        vr = *(const u16x8*)vg;
    }
    *(u16x8*)&Kl[sj][sw] = kr;
    *(u16x8*)&Vl[sj][sw] = vr;
    __syncthreads();

    for (int k0 = kbeg; k0 < kend; k0 += 64) {
        const bool has_next = (k0 + 64 < kend);
        if (has_next) {
            const u16* kg = Kb + kvbase + (size_t)(k0 + 64 + sj) * 64 + sc * 8;
            kr = *(const u16x8*)kg;
            const u16* vg = Vt + kvbase + (size_t)sj * 2048 + k0 + 64 + sc * 8;
            vr = *(const u16x8*)vg;
        }

        bool active = (k0 <= wrow_max) && (k0 + 63 >= wrow_min - (WINDOW - 1));
        if (active) {
            f32x4 s[4];
            #pragma unroll
            for (int nf = 0; nf < 4; ++nf) {
                bf16x8 kb0 = ld_bf8(&Kl[nf * 16 + q][ca0]);
                bf16x8 kb1 = ld_bf8(&Kl[nf * 16 + q][ca1]);
                f32x4 a = {};
                a = __builtin_amdgcn_mfma_f32_16x16x32_bf16(kb0, qf0, a, 0, 0, 0);
                a = __builtin_amdgcn_mfma_f32_16x16x32_bf16(kb1, qf1, a, 0, 0, 0);
                s[nf] = a;
            }
            bool need_causal = (k0 + 63 > wrow_min);
            bool need_window = (wrow_max - k0) >= WINDOW;
            if (need_causal || need_window) {
                #pragma unroll
                for (int nf = 0; nf < 4; ++nf) {
                    #pragma unroll
                    for (int r = 0; r < 4; ++r) {
                        int j = k0 + nf * 16 + hq * 4 + r;
                        bool ok = (j <= iq) && (iq - j < WINDOW);
                        if (!ok) s[nf][r] = -1e30f;
                    }
                }
            }
            float tmax = s[0][0];
            #pragma unroll
            for (int nf = 0; nf < 4; ++nf)
                #pragma unroll
                for (int r = 0; r < 4; ++r) tmax = fmaxf(tmax, s[nf][r]);
            tmax = fmaxf(tmax, __shfl_xor(tmax, 16));
            tmax = fmaxf(tmax, __shfl_xor(tmax, 32));

            bool skip = __all(tmax <= mrun + 11.5f);
            float mnew = skip ? mrun : fmaxf(mrun, tmax);

            float tsum = 0.f;
            #pragma unroll
            for (int nf = 0; nf < 4; ++nf) {
                float p0 = exp2f_raw(s[nf][0] - mnew);
                float p1 = exp2f_raw(s[nf][1] - mnew);
                float p2 = exp2f_raw(s[nf][2] - mnew);
                float p3 = exp2f_raw(s[nf][3] - mnew);
                tsum += (p0 + p1) + (p2 + p3);
                u32x2 pw = { cvt_pk_bf16(p0, p1), cvt_pk_bf16(p2, p3) };
                int cpw = (((2 * nf + (hq >> 1)) ^ (q & 7)) << 3) + ((hq & 1) << 2);
                *(u32x2*)&Pl[w][q][cpw] = pw;
            }
            tsum += __shfl_xor(tsum, 16);
            tsum += __shfl_xor(tsum, 32);

            if (skip) {
                lrun += tsum;
            } else {
                float sc2 = exp2f_raw(mrun - mnew);
                mrun = mnew;
                lrun = lrun * sc2 + tsum;
                float osc[4];
                #pragma unroll
                for (int r = 0; r < 4; ++r)
                    osc[r] = __shfl(sc2, (lane & 48) + hq * 4 + r);
                #pragma unroll
                for (int nf = 0; nf < 4; ++nf)
                    #pragma unroll
                    for (int r = 0; r < 4; ++r)
                        o[nf][r] *= osc[r];
            }

            bf16x8 pa0 = ld_bf8(&Pl[w][q][ca0]);
            bf16x8 pa1 = ld_bf8(&Pl[w][q][ca1]);
            #pragma unroll
            for (int nf = 0; nf < 4; ++nf) {
                bf16x8 vb0 = ld_bf8(&Vl[nf * 16 + q][ca0]);
                bf16x8 vb1 = ld_bf8(&Vl[nf * 16 + q][ca1]);
                o[nf] = __builtin_amdgcn_mfma_f32_16x16x32_bf16(pa0, vb0, o[nf], 0, 0, 0);
                o[nf] = __builtin_amdgcn_mfma_f32_16x16x32_bf16(pa1, vb1, o[nf], 0, 0, 0);
            }
        }
        __syncthreads();
        if (has_next) {
            *(u16x8*)&Kl[sj][sw] = kr;
            *(u16x8*)&Vl[sj][sw] = vr;
        }
        __syncthreads();
    }

    float linv_own = 1.f / lrun;
    float linv[4];
    #pragma unroll
    for (int r = 0; r < 4; ++r)
        linv[r] = __shfl(linv_own, (lane & 48) + hq * 4 + r);
    #pragma unroll
    for (int nf = 0; nf < 4; ++nf) {
        #pragma unroll
        for (int r = 0; r < 4; ++r) {
            int i = q0 + w * 16 + hq * 4 + r;
            int d = nf * 16 + q;
            AO[((size_t)b * 2048 + i) * 2048 + h * 64 + d] = f2bf(o[nf][r] * linv[r]);
        }
    }
}

extern "C" void kernel_launch(void* const* d_in, const int* in_sizes, int n_in,
                              void* d_out, int out_size, void* d_ws, size_t ws_size,
                              hipStream_t stream)
{
    const float* x  = (const float*)d_in[0];
    const float* Wq = (const float*)d_in[1];
    const float* Wk = (const float*)d_in[2];
    const float* Wv = (const float*)d_in[3];
    const float* Wo = (const float*)d_in[4];
    float* out = (float*)d_out;

    u16* Qb    = (u16*)d_ws;                              //  8,388,608
    u16* Kb    = Qb    + (size_t)8388608;                 //  2,097,152
    u16* Vb    = Kb    + (size_t)2097152;                 //  2,097,152
    u16* Vt    = Vb    + (size_t)2097152;                 //  2,097,152
    u16* AO    = Vt    + (size_t)2097152;                 //  8,388,608
    u16* xb    = AO    + (size_t)8388608;                 //  8,388,608
    u16* WqkvT = xb    + (size_t)8388608;                 //  6,291,456  [3072][2048]
    u16* WoT   = WqkvT + (size_t)6291456;                 //  4,194,304  [2048][2048]
    float2* tab = (float2*)(WoT + (size_t)4194304);       //  512KB

    rope_tab_kernel<<<256, 256, 0, stream>>>(tab);
    convert_x<<<4096, 256, 0, stream>>>(x, xb);
    trans_conv_all<<<dim3(32, 32, 4), 256, 0, stream>>>(Wq, Wk, Wv, Wo, WqkvT, WoT);

    qkv_gemm<<<dim3(32, 24), 128, 0, stream>>>(xb, WqkvT, tab, Qb, Kb, Vb);
    vtrans<<<dim3(32, 16), 256, 0, stream>>>(Vb, Vt);
    attn_kernel<<<dim3(64, 16), 512, 0, stream>>>(Qb, Kb, Vt, AO);
    out_gemm<<<dim3(32, 16), 128, 0, stream>>>(AO, WoT, out);
}

// Round 13
// 178.603 us; speedup vs baseline: 1.3968x; 1.0548x over previous
//
#include <hip/hip_runtime.h>

typedef unsigned short u16;
typedef __attribute__((ext_vector_type(8))) unsigned short u16x8;
typedef __attribute__((ext_vector_type(2))) unsigned int u32x2;
typedef __attribute__((ext_vector_type(8))) __bf16 bf16x8;
typedef __attribute__((ext_vector_type(4))) float f32x4;

#define T_SEQ 2048
#define WINDOW 1024
// 0.125 * log2(e)
#define QSCALE 0.18033688011112042f

static __device__ __forceinline__ u16 f2bf(float f) {
    unsigned int u = __float_as_uint(f);
    u += 0x7fffu + ((u >> 16) & 1u);
    return (u16)(u >> 16);
}
static __device__ __forceinline__ float bf2f(u16 h) {
    return __uint_as_float(((unsigned int)h) << 16);
}
static __device__ __forceinline__ bf16x8 ld_bf8(const u16* p) {
    return __builtin_bit_cast(bf16x8, *(const u16x8*)p);
}
static __device__ __forceinline__ unsigned int cvt_pk_bf16(float lo, float hi) {
    unsigned int r;
    asm("v_cvt_pk_bf16_f32 %0, %1, %2" : "=v"(r) : "v"(lo), "v"(hi));
    return r;
}
static __device__ __forceinline__ float exp2f_raw(float x) {
#if __has_builtin(__builtin_amdgcn_exp2f)
    return __builtin_amdgcn_exp2f(x);
#else
    return exp2f(x);
#endif
}
// async global -> LDS, 16B per lane (wave-uniform LDS base + lane*16)
static __device__ __forceinline__ void g2l16(const void* g, void* l) {
    __builtin_amdgcn_global_load_lds(
        (const __attribute__((address_space(1))) void*)g,
        (__attribute__((address_space(3))) void*)l, 16, 0, 0);
}

// per-CU work-balance permutation for attn q-tiles: quartets {a,a+4,a+8,a+12}
// map to tile-counts summing to exactly 54 each (see round-11 analysis)
__device__ const int q_tmap[16] = {0, 1, 2, 3, 7, 6, 5, 4, 8, 10, 12, 14, 9, 11, 13, 15};

// ---------------- RoPE cos/sin table: float2[2048][32] ----------------
__global__ __launch_bounds__(256)
void rope_tab_kernel(float2* __restrict__ tab)
{
    int idx = blockIdx.x * 256 + threadIdx.x;   // 65536
    int t = idx >> 5, dp = idx & 31;
    float inv_freq = __expf(-dp * 0.28782313662425574f); // ln(10000)/32
    float ang = (float)t * inv_freq;
    float s, c;
    sincosf(ang, &s, &c);
    tab[idx] = make_float2(c, s);
}

// ---------------- x fp32 -> bf16 (same layout) ----------------
__global__ __launch_bounds__(256)
void convert_x(const float* __restrict__ src, u16* __restrict__ dst)
{
    int i8 = blockIdx.x * 256 + threadIdx.x;
    size_t base = (size_t)i8 * 8;
    float4 a = *(const float4*)(src + base);
    float4 b = *(const float4*)(src + base + 4);
    u16x8 o = { f2bf(a.x), f2bf(a.y), f2bf(a.z), f2bf(a.w),
                f2bf(b.x), f2bf(b.y), f2bf(b.z), f2bf(b.w) };
    *(u16x8*)(dst + base) = o;
}

// ---------------- all W fp32 [2048][N] -> bf16 transposed [N][2048], scaled ----------------
__global__ __launch_bounds__(256)
void trans_conv_all(const float* __restrict__ Wq, const float* __restrict__ Wk,
                    const float* __restrict__ Wv, const float* __restrict__ Wo,
                    u16* __restrict__ WqkvT, u16* __restrict__ WoT)
{
    __shared__ __align__(16) u16 tile[64][72];
    const int z = blockIdx.z;
    const float* src; int N; float scale; u16* dst;
    if (z == 0)      { src = Wq; N = 2048; scale = QSCALE; dst = WqkvT; }
    else if (z == 1) { src = Wk; N = 512;  scale = 1.f;    dst = WqkvT + (size_t)2048 * 2048; }
    else if (z == 2) { src = Wv; N = 512;  scale = 1.f;    dst = WqkvT + (size_t)2560 * 2048; }
    else             { src = Wo; N = 2048; scale = 1.f;    dst = WoT; }
    if ((int)blockIdx.y * 64 >= N) return;

    const int tid = threadIdx.x;
    const int k0 = blockIdx.x * 64;
    const int n0 = blockIdx.y * 64;
    {
        int r = tid >> 2, c0 = (tid & 3) * 16;
        const float* sp = src + (size_t)(k0 + r) * N + n0 + c0;
        float4 v0 = *(const float4*)(sp + 0);
        float4 v1 = *(const float4*)(sp + 4);
        float4 v2 = *(const float4*)(sp + 8);
        float4 v3 = *(const float4*)(sp + 12);
        u16x8 s0 = { f2bf(v0.x * scale), f2bf(v0.y * scale), f2bf(v0.z * scale), f2bf(v0.w * scale),
                     f2bf(v1.x * scale), f2bf(v1.y * scale), f2bf(v1.z * scale), f2bf(v1.w * scale) };
        u16x8 s1 = { f2bf(v2.x * scale), f2bf(v2.y * scale), f2bf(v2.z * scale), f2bf(v2.w * scale),
                     f2bf(v3.x * scale), f2bf(v3.y * scale), f2bf(v3.z * scale), f2bf(v3.w * scale) };
        *(u16x8*)&tile[r][c0]     = s0;
        *(u16x8*)&tile[r][c0 + 8] = s1;
    }
    __syncthreads();
    {
        int n = tid >> 2, j0 = (tid & 3) * 16;
        u16x8 o0, o1;
        #pragma unroll
        for (int i = 0; i < 8; ++i) o0[i] = tile[j0 + i][n];
        #pragma unroll
        for (int i = 0; i < 8; ++i) o1[i] = tile[j0 + 8 + i][n];
        u16* dp = dst + (size_t)(n0 + n) * 2048 + k0 + j0;
        *(u16x8*)dp       = o0;
        *(u16x8*)(dp + 8) = o1;
    }
}

// ================= GEMM core: 256 threads (4 waves, 2x2), block 128x128 =================
// per-wave 64x64, BK=64, XOR-swizzled conflict-free LDS, g2l16 staging.
__device__ __forceinline__ void gemm_core_256(const u16* __restrict__ Ag,
                                              const u16* __restrict__ Bg,
                                              u16 (*Al)[64], u16 (*Bl)[64],
                                              int lane, int w, f32x4 acc[4][4])
{
    const int wm = w >> 1, wn = w & 1;
    const int r8 = lane >> 3;             // row-within-8 of staging
    const int cs = (lane & 7) ^ r8;       // inverse-swizzled source chunk
    // wave w stages rows [w*32, w*32+32) in 4 instructions of 8 rows
    const u16* ag = Ag + (size_t)(w * 32 + r8) * 2048 + cs * 8;
    const u16* bg = Bg + (size_t)(w * 32 + r8) * 2048 + cs * 8;
    const int fr = lane & 15;
    const int hq = lane >> 4;

    for (int kb = 0; kb < 2048; kb += 64) {
        #pragma unroll
        for (int j = 0; j < 4; ++j)
            g2l16(ag + (size_t)(j * 8) * 2048 + kb, &Al[w * 32 + j * 8][0]);
        #pragma unroll
        for (int j = 0; j < 4; ++j)
            g2l16(bg + (size_t)(j * 8) * 2048 + kb, &Bl[w * 32 + j * 8][0]);
        __syncthreads();

        #pragma unroll
        for (int kk = 0; kk < 2; ++kk) {
            bf16x8 af[4], bfn[4];
            #pragma unroll
            for (int m = 0; m < 4; ++m) {
                int row = wm * 64 + m * 16 + fr;
                int pc = (kk * 4 + hq) ^ (row & 7);
                af[m] = ld_bf8(&Al[row][pc * 8]);
            }
            #pragma unroll
            for (int n = 0; n < 4; ++n) {
                int row = wn * 64 + n * 16 + fr;
                int pc = (kk * 4 + hq) ^ (row & 7);
                bfn[n] = ld_bf8(&Bl[row][pc * 8]);
            }
            #pragma unroll
            for (int m = 0; m < 4; ++m)
                #pragma unroll
                for (int n = 0; n < 4; ++n)
                    acc[m][n] = __builtin_amdgcn_mfma_f32_16x16x32_bf16(af[m], bfn[n], acc[m][n], 0, 0, 0);
        }
        __syncthreads();
    }
}

// ---------------- QKV GEMM + fused RoPE epilogue ----------------
__global__ __launch_bounds__(256, 3)
void qkv_gemm(const u16* __restrict__ xb, const u16* __restrict__ Wt,
              const float2* __restrict__ tab,
              u16* __restrict__ Qb, u16* __restrict__ Kb, u16* __restrict__ Vb)
{
    __shared__ __align__(16) u16 Al[128][64];
    __shared__ __align__(16) u16 Bl[128][64];
    const int tid = threadIdx.x;
    const int lane = tid & 63;
    const int w = tid >> 6;
    const int wm = w >> 1, wn = w & 1;
    const int m0  = blockIdx.x * 128;
    const int n0g = blockIdx.y * 128;

    f32x4 acc[4][4] = {};
    gemm_core_256(xb + (size_t)m0 * 2048, Wt + (size_t)n0g * 2048, Al, Bl, lane, w, acc);

    const int hq = lane >> 4;
    const int c0 = lane & 15;
    const int colbase = n0g + wn * 64;         // multiple of 64
    const bool isV = (n0g >= 2560);
    const bool isQ = (n0g < 2048);

    #pragma unroll
    for (int m = 0; m < 4; ++m) {
        #pragma unroll
        for (int r = 0; r < 4; ++r) {
            int rw = m0 + wm * 64 + m * 16 + hq * 4 + r;
            int b = rw >> 11, t = rw & 2047;
            if (!isV) {
                #pragma unroll
                for (int np = 0; np < 2; ++np) {
                    int dp = np * 16 + c0;
                    float2 cs = tab[t * 32 + dp];
                    float x1 = acc[m][np][r];
                    float x2 = acc[m][np + 2][r];
                    float lo = x1 * cs.x - x2 * cs.y;
                    float hi = x2 * cs.x + x1 * cs.y;
                    if (isQ) {
                        int h = colbase >> 6;
                        size_t base = (((size_t)b * 32 + h) * 2048 + t) * 64 + dp;
                        Qb[base]      = f2bf(lo);
                        Qb[base + 32] = f2bf(hi);
                    } else {
                        int hk = (colbase - 2048) >> 6;
                        size_t base = (((size_t)b * 8 + hk) * 2048 + t) * 64 + dp;
                        Kb[base]      = f2bf(lo);
                        Kb[base + 32] = f2bf(hi);
                    }
                }
            } else {
                #pragma unroll
                for (int n = 0; n < 4; ++n) {
                    int c2 = colbase + n * 16 + c0 - 2560;
                    int hk = c2 >> 6, d = c2 & 63;
                    Vb[(((size_t)b * 8 + hk) * 2048 + t) * 64 + d] = f2bf(acc[m][n][r]);
                }
            }
        }
    }
}

// ---------------- Output projection ----------------
__global__ __launch_bounds__(256, 3)
void out_gemm(const u16* __restrict__ A, const u16* __restrict__ Wt, float* __restrict__ C)
{
    __shared__ __align__(16) u16 Al[128][64];
    __shared__ __align__(16) u16 Bl[128][64];
    const int tid = threadIdx.x;
    const int lane = tid & 63;
    const int w = tid >> 6;
    const int wm = w >> 1, wn = w & 1;
    const int m0 = blockIdx.x * 128;
    const int n0 = blockIdx.y * 128;

    f32x4 acc[4][4] = {};
    gemm_core_256(A + (size_t)m0 * 2048, Wt + (size_t)n0 * 2048, Al, Bl, lane, w, acc);

    const int hq = lane >> 4;
    const int c0 = lane & 15;
    #pragma unroll
    for (int m = 0; m < 4; ++m) {
        #pragma unroll
        for (int n = 0; n < 4; ++n) {
            #pragma unroll
            for (int r = 0; r < 4; ++r) {
                int rw = m0 + wm * 64 + m * 16 + hq * 4 + r;
                int col = n0 + wn * 64 + n * 16 + c0;
                C[(size_t)rw * 2048 + col] = acc[m][n][r];
            }
        }
    }
}

// ---------------- V transpose: (b,hk,t,d) -> (b,hk,d,t) ----------------
__global__ __launch_bounds__(256)
void vtrans(const u16* __restrict__ Vb, u16* __restrict__ Vt)
{
    __shared__ __align__(16) u16 tile[64][68];
    const int tid = threadIdx.x;
    const int t0 = blockIdx.x * 64;
    const size_t base = (size_t)blockIdx.y * 2048 * 64;
    {
        int r = tid >> 2, c0 = (tid & 3) * 16;
        const u16* src = Vb + base + (size_t)(t0 + r) * 64 + c0;
        *(u16x8*)&tile[r][c0]     = *(const u16x8*)src;
        *(u16x8*)&tile[r][c0 + 8] = *(const u16x8*)(src + 8);
    }
    __syncthreads();
    {
        int d = tid >> 2, j0 = (tid & 3) * 16;
        u16x8 o0, o1;
        #pragma unroll
        for (int i = 0; i < 8; ++i) o0[i] = tile[j0 + i][d];
        #pragma unroll
        for (int i = 0; i < 8; ++i) o1[i] = tile[j0 + 8 + i][d];
        u16* dst = Vt + base + (size_t)d * 2048 + t0 + j0;
        *(u16x8*)dst       = o0;
        *(u16x8*)(dst + 8) = o1;
    }
}

// ---------------- Flash attention: 8 waves, QBLK=128, CU-work-balanced grid ----------------
__global__ __launch_bounds__(512)
void attn_kernel(const u16* __restrict__ Qb, const u16* __restrict__ Kb,
                 const u16* __restrict__ Vt, u16* __restrict__ AO)
{
    __shared__ __align__(16) u16 Kl[64][64];    // XOR-swizzled 16B chunks
    __shared__ __align__(16) u16 Vl[64][64];    // Vl[d][j], swizzled
    __shared__ __align__(16) u16 Pl[8][16][64]; // per-wave [q][k], swizzled

    const int tid = threadIdx.x;
    const int lane = tid & 63;
    const int w = tid >> 6;                 // 0..7
    const int q = lane & 15;
    const int hq = lane >> 4;
    const int q0 = q_tmap[blockIdx.y] * 128;   // balanced q-tile per CU quartet
    const int bh = blockIdx.x;                 // bh fast -> CU quartets span q-tiles
    const int b = bh >> 5, h = bh & 31;
    const int hk = h >> 2;
    const size_t qbase  = (size_t)bh * 2048 * 64;
    const size_t kvbase = ((size_t)b * 8 + hk) * 2048 * 64;

    // staging: one 16B chunk per thread per array (512 thr = 64 rows x 8 chunks)
    const int sj = tid >> 3;                // row 0..63
    const int sc = tid & 7;                 // logical chunk
    const int sw = (sc ^ (sj & 7)) << 3;    // swizzled phys offset (u16 units)
    const int ca0 = ((hq    ) ^ (q & 7)) << 3;
    const int ca1 = ((hq + 4) ^ (q & 7)) << 3;

    bf16x8 qf0, qf1;
    {
        const u16* qp = Qb + qbase + (size_t)(q0 + w * 16 + q) * 64 + hq * 8;
        qf0 = ld_bf8(qp);
        qf1 = ld_bf8(qp + 32);
    }

    float mrun = -1e20f, lrun = 0.f;
    f32x4 o[4] = {};

    int kbeg = q0 - (WINDOW - 1);
    if (kbeg < 0) kbeg = 0;
    kbeg &= ~63;
    const int kend = q0 + 128;

    const int wrow_min = q0 + w * 16;
    const int wrow_max = wrow_min + 15;
    const int iq = wrow_min + q;

    u16x8 kr, vr;
    {
        const u16* kg = Kb + kvbase + (size_t)(kbeg + sj) * 64 + sc * 8;
        kr = *(const u16x8*)kg;
        const u16* vg = Vt + kvbase + (size_t)sj * 2048 + kbeg + sc * 8;
        vr = *(const u16x8*)vg;
    }
    *(u16x8*)&Kl[sj][sw] = kr;
    *(u16x8*)&Vl[sj][sw] = vr;
    __syncthreads();

    for (int k0 = kbeg; k0 < kend; k0 += 64) {
        const bool has_next = (k0 + 64 < kend);
        if (has_next) {
            const u16* kg = Kb + kvbase + (size_t)(k0 + 64 + sj) * 64 + sc * 8;
            kr = *(const u16x8*)kg;
            const u16* vg = Vt + kvbase + (size_t)sj * 2048 + k0 + 64 + sc * 8;
            vr = *(const u16x8*)vg;
        }

        bool active = (k0 <= wrow_max) && (k0 + 63 >= wrow_min - (WINDOW - 1));
        if (active) {
            f32x4 s[4];
            #pragma unroll
            for (int nf = 0; nf < 4; ++nf) {
                bf16x8 kb0 = ld_bf8(&Kl[nf * 16 + q][ca0]);
                bf16x8 kb1 = ld_bf8(&Kl[nf * 16 + q][ca1]);
                f32x4 a = {};
                a = __builtin_amdgcn_mfma_f32_16x16x32_bf16(kb0, qf0, a, 0, 0, 0);
                a = __builtin_amdgcn_mfma_f32_16x16x32_bf16(kb1, qf1, a, 0, 0, 0);
                s[nf] = a;
            }
            bool need_causal = (k0 + 63 > wrow_min);
            bool need_window = (wrow_max - k0) >= WINDOW;
            if (need_causal || need_window) {
                #pragma unroll
                for (int nf = 0; nf < 4; ++nf) {
                    #pragma unroll
                    for (int r = 0; r < 4; ++r) {
                        int j = k0 + nf * 16 + hq * 4 + r;
                        bool ok = (j <= iq) && (iq - j < WINDOW);
                        if (!ok) s[nf][r] = -1e30f;
                    }
                }
            }
            float tmax = s[0][0];
            #pragma unroll
            for (int nf = 0; nf < 4; ++nf)
                #pragma unroll
                for (int r = 0; r < 4; ++r) tmax = fmaxf(tmax, s[nf][r]);
            tmax = fmaxf(tmax, __shfl_xor(tmax, 16));
            tmax = fmaxf(tmax, __shfl_xor(tmax, 32));

            bool skip = __all(tmax <= mrun + 11.5f);
            float mnew = skip ? mrun : fmaxf(mrun, tmax);

            float tsum = 0.f;
            #pragma unroll
            for (int nf = 0; nf < 4; ++nf) {
                float p0 = exp2f_raw(s[nf][0] - mnew);
                float p1 = exp2f_raw(s[nf][1] - mnew);
                float p2 = exp2f_raw(s[nf][2] - mnew);
                float p3 = exp2f_raw(s[nf][3] - mnew);
                tsum += (p0 + p1) + (p2 + p3);
                u32x2 pw = { cvt_pk_bf16(p0, p1), cvt_pk_bf16(p2, p3) };
                int cpw = (((2 * nf + (hq >> 1)) ^ (q & 7)) << 3) + ((hq & 1) << 2);
                *(u32x2*)&Pl[w][q][cpw] = pw;
            }
            tsum += __shfl_xor(tsum, 16);
            tsum += __shfl_xor(tsum, 32);

            if (skip) {
                lrun += tsum;
            } else {
                float sc2 = exp2f_raw(mrun - mnew);
                mrun = mnew;
                lrun = lrun * sc2 + tsum;
                float osc[4];
                #pragma unroll
                for (int r = 0; r < 4; ++r)
                    osc[r] = __shfl(sc2, (lane & 48) + hq * 4 + r);
                #pragma unroll
                for (int nf = 0; nf < 4; ++nf)
                    #pragma unroll
                    for (int r = 0; r < 4; ++r)
                        o[nf][r] *= osc[r];
            }

            bf16x8 pa0 = ld_bf8(&Pl[w][q][ca0]);
            bf16x8 pa1 = ld_bf8(&Pl[w][q][ca1]);
            #pragma unroll
            for (int nf = 0; nf < 4; ++nf) {
                bf16x8 vb0 = ld_bf8(&Vl[nf * 16 + q][ca0]);
                bf16x8 vb1 = ld_bf8(&Vl[nf * 16 + q][ca1]);
                o[nf] = __builtin_amdgcn_mfma_f32_16x16x32_bf16(pa0, vb0, o[nf], 0, 0, 0);
                o[nf] = __builtin_amdgcn_mfma_f32_16x16x32_bf16(pa1, vb1, o[nf], 0, 0, 0);
            }
        }
        __syncthreads();
        if (has_next) {
            *(u16x8*)&Kl[sj][sw] = kr;
            *(u16x8*)&Vl[sj][sw] = vr;
        }
        __syncthreads();
    }

    float linv_own = 1.f / lrun;
    float linv[4];
    #pragma unroll
    for (int r = 0; r < 4; ++r)
        linv[r] = __shfl(linv_own, (lane & 48) + hq * 4 + r);
    #pragma unroll
    for (int nf = 0; nf < 4; ++nf) {
        #pragma unroll
        for (int r = 0; r < 4; ++r) {
            int i = q0 + w * 16 + hq * 4 + r;
            int d = nf * 16 + q;
            AO[((size_t)b * 2048 + i) * 2048 + h * 64 + d] = f2bf(o[nf][r] * linv[r]);
        }
    }
}

extern "C" void kernel_launch(void* const* d_in, const int* in_sizes, int n_in,
                              void* d_out, int out_size, void* d_ws, size_t ws_size,
                              hipStream_t stream)
{
    const float* x  = (const float*)d_in[0];
    const float* Wq = (const float*)d_in[1];
    const float* Wk = (const float*)d_in[2];
    const float* Wv = (const float*)d_in[3];
    const float* Wo = (const float*)d_in[4];
    float* out = (float*)d_out;

    u16* Qb    = (u16*)d_ws;                              //  8,388,608
    u16* Kb    = Qb    + (size_t)8388608;                 //  2,097,152
    u16* Vb    = Kb    + (size_t)2097152;                 //  2,097,152
    u16* Vt    = Vb    + (size_t)2097152;                 //  2,097,152
    u16* AO    = Vt    + (size_t)2097152;                 //  8,388,608
    u16* xb    = AO    + (size_t)8388608;                 //  8,388,608
    u16* WqkvT = xb    + (size_t)8388608;                 //  6,291,456  [3072][2048]
    u16* WoT   = WqkvT + (size_t)6291456;                 //  4,194,304  [2048][2048]
    float2* tab = (float2*)(WoT + (size_t)4194304);       //  512KB

    rope_tab_kernel<<<256, 256, 0, stream>>>(tab);
    convert_x<<<4096, 256, 0, stream>>>(x, xb);
    trans_conv_all<<<dim3(32, 32, 4), 256, 0, stream>>>(Wq, Wk, Wv, Wo, WqkvT, WoT);

    qkv_gemm<<<dim3(32, 24), 256, 0, stream>>>(xb, WqkvT, tab, Qb, Kb, Vb);
    vtrans<<<dim3(32, 16), 256, 0, stream>>>(Vb, Vt);
    attn_kernel<<<dim3(64, 16), 512, 0, stream>>>(Qb, Kb, Vt, AO);
    out_gemm<<<dim3(32, 16), 256, 0, stream>>>(AO, WoT, out);
}